// Round 3
// baseline (420.191 us; speedup 1.0000x reference)
//
#include <hip/hip_runtime.h>
#include <math.h>

#define F_MH 4
#define NB   512
#define SEQ  2048
#define TOPK 128
#define EDIM 64
#define ADIM 128
#define VOH  10001
#define VMH  100001
#define NROWS (F_MH * VMH)   // 400004
#define D0   1728
#define RSQRT32 0.17677669529663687f

typedef __bf16 bf16x8 __attribute__((ext_vector_type(8)));
typedef __bf16 bf16x4 __attribute__((ext_vector_type(4)));
typedef float  f32x4  __attribute__((ext_vector_type(4)));

// ---------------------------------------------------------------------------
// K_ph (R9): merged k_prep (weight transposes + attn-weight folding, blocks
// 0..2399) and k_hash (LSH signatures via bf16 hi/lo split MFMA, blocks
// 2400..3181). Independent workloads; merging removes one launch gap and
// overlaps prep's memory-streaming tail with hash's MFMA+VALU blocks.
// ---------------------------------------------------------------------------
__global__ __launch_bounds__(256) void k_ph(
    const float* __restrict__ W0x, const float* __restrict__ W1x, const float* __restrict__ W2x,
    __bf16* __restrict__ WT0, __bf16* __restrict__ WT1, __bf16* __restrict__ WT2,
    const float* __restrict__ sqW, const float* __restrict__ sqb,
    const float* __restrict__ skW,
    const float* __restrict__ svW, const float* __restrict__ svb,
    const float* __restrict__ soW, const float* __restrict__ sob,
    const float* __restrict__ lqW, const float* __restrict__ lqb,
    const float* __restrict__ lkW,
    const float* __restrict__ lvW, const float* __restrict__ lvb,
    const float* __restrict__ loW, const float* __restrict__ lob,
    float* __restrict__ Mq, float* __restrict__ B1,
    float* __restrict__ VO, float* __restrict__ bvo,
    const float* __restrict__ tab, const float* __restrict__ hw,
    unsigned int* __restrict__ sig)
{
    __shared__ __align__(16) float smem[8704];   // 34816 B: max(prep 8416, hash 128*68)
    const int bid = blockIdx.x, t = threadIdx.x;

    if (bid < 2368) {
        // ---- transpose branch ----
        const float* W; __bf16* WT; int N, K, base, nbs;
        if (bid < 1728)      { W = W0x; WT = WT0; K = 1728; N = 1024; base = 0;    nbs = 5; }
        else if (bid < 2240) { W = W1x; WT = WT1; K = 1024; N = 512;  base = 1728; nbs = 4; }
        else                 { W = W2x; WT = WT2; K = 512;  N = 256;  base = 2240; nbs = 3; }
        const int lb = bid - base;
        const int n0 = (lb & ((1 << nbs) - 1)) * 32, k0 = (lb >> nbs) * 32;
        float (*tile)[33] = (float(*)[33])smem;
        const int c = t & 31, r = t >> 5;
#pragma unroll
        for (int i = 0; i < 4; ++i)
            tile[r + 8 * i][c] = W[(size_t)(k0 + r + 8 * i) * N + n0 + c];
        __syncthreads();
#pragma unroll
        for (int i = 0; i < 4; ++i)
            WT[(size_t)(n0 + r + 8 * i) * K + k0 + c] = (__bf16)tile[c][r + 8 * i];
    } else if (bid < 2400) {
        // ---- attn-weight fold branch ----
        const int idx = bid - 2368;
        const int f = idx & 3, z = (idx >> 2) & 1, h = idx >> 3;
        const float* WQ = (z ? lqW : sqW) + (size_t)f * 8192;
        const float* bq = (z ? lqb : sqb) + f * 128;
        const float* WK = (z ? lkW : skW) + (size_t)f * 8192;
        const float* WV = (z ? lvW : svW) + (size_t)f * 8192;
        const float* bv = (z ? lvb : svb) + f * 128;
        const float* WO = (z ? loW : soW) + (size_t)f * 8192;
        const float* bo = (z ? lob : sob) + f * 64;
        float (*wq)[33] = (float(*)[33])smem;
        float (*wk)[33] = (float(*)[33])(smem + 2112);
        float (*wv)[33] = (float(*)[33])(smem + 4224);
        float (*wo)[65] = (float(*)[65])(smem + 6336);
#pragma unroll
        for (int i = 0; i < 8; ++i) {
            int j = t + i * 256;
            wq[j >> 5][j & 31] = WQ[(j >> 5) * 128 + h * 32 + (j & 31)];
            wk[j >> 5][j & 31] = WK[(j >> 5) * 128 + h * 32 + (j & 31)];
            wv[j >> 5][j & 31] = WV[(j >> 5) * 128 + h * 32 + (j & 31)];
            wo[j >> 6][j & 63] = WO[(h * 32 + (j >> 6)) * 64 + (j & 63)];
        }
        __syncthreads();
        const int lane = t & 63, grp = t >> 6;
        float* Mqb = Mq + (size_t)(((z * 4 + f) * 4 + h)) * 4096;
        float* VOb = VO + (size_t)(((z * 4 + f) * 4 + h)) * 4096;
#pragma unroll 4
        for (int g = 0; g < 16; ++g) {
            const int ep = grp * 16 + g;
            float am = 0.f, av = 0.f;
#pragma unroll
            for (int d = 0; d < 32; ++d) {
                am += wq[ep][d] * wk[lane][d];
                av += wv[ep][d] * wo[d][lane];
            }
            Mqb[ep * 64 + lane] = am;
            VOb[ep * 64 + lane] = av;
        }
        if (t < 64) {
            float acc = 0.f;
#pragma unroll
            for (int d = 0; d < 32; ++d) acc += bq[h * 32 + d] * wk[t][d];
            B1[((z * 4 + f) * 4 + h) * 64 + t] = acc;
        }
        if (h == 0 && t >= 64 && t < 128) {
            const int o = t - 64;
            float acc = bo[o];
            for (int a = 0; a < 128; ++a) acc += bv[a] * WO[a * 64 + o];
            bvo[(z * 4 + f) * 64 + o] = acc;
        }
    } else {
        // ---- LSH hash branch ----
        const int hb = bid - 2400;
        float (*rows)[68] = (float(*)[68])smem;   // pitch 68: 16B-aligned b128
        const int lane = t & 63, wave = t >> 6;
        const int m = lane & 15, quad = lane >> 4;

        bf16x8 whf[2][2], wlf[2][2];
#pragma unroll
        for (int ks = 0; ks < 2; ++ks)
#pragma unroll
            for (int hf = 0; hf < 2; ++hf) {
                bf16x8 bh, bl;
#pragma unroll
                for (int j = 0; j < 8; ++j) {
                    const float w = hw[(ks * 32 + quad * 8 + j) * 32 + hf * 16 + m];
                    const __bf16 h = (__bf16)w;
                    bh[j] = h;
                    bl[j] = (__bf16)(w - (float)h);
                }
                whf[ks][hf] = bh; wlf[ks][hf] = bl;
            }

        const long long base_dw = (long long)hb * 32768;   // 512 rows * 64
        const long long lim = (long long)NROWS * 64;
        float4 pf[8];
#pragma unroll
        for (int i = 0; i < 8; ++i) {
            const long long idx = base_dw + i * 1024 + t * 4;
            pf[i] = make_float4(0.f, 0.f, 0.f, 0.f);
            if (idx < lim) pf[i] = *(const float4*)(tab + idx);
        }
        for (int c = 0; c < 4; ++c) {
            __syncthreads();              // prior chunk's LDS reads done
#pragma unroll
            for (int i = 0; i < 8; ++i) {
                const int v = t + i * 256;              // float4 index 0..2047
                *(float4*)&rows[v >> 4][(v & 15) << 2] = pf[i];
            }
            __syncthreads();
            if (c < 3) {                  // prefetch next chunk under compute
#pragma unroll
                for (int i = 0; i < 8; ++i) {
                    const long long idx = base_dw + (long long)(c + 1) * 8192 + i * 1024 + t * 4;
                    pf[i] = make_float4(0.f, 0.f, 0.f, 0.f);
                    if (idx < lim) pf[i] = *(const float4*)(tab + idx);
                }
            }
#pragma unroll
            for (int tile = 0; tile < 2; ++tile) {
                const int rbase = wave * 32 + tile * 16;
                f32x4 acc0 = {0.f, 0.f, 0.f, 0.f}, acc1 = {0.f, 0.f, 0.f, 0.f};
#pragma unroll
                for (int ks = 0; ks < 2; ++ks) {
                    const float* src = &rows[rbase + m][ks * 32 + quad * 8];
                    const float4 x0 = *(const float4*)(src);
                    const float4 x1 = *(const float4*)(src + 4);
                    float xs[8] = {x0.x, x0.y, x0.z, x0.w, x1.x, x1.y, x1.z, x1.w};
                    bf16x8 ah, al;
#pragma unroll
                    for (int j = 0; j < 8; ++j) {
                        const __bf16 hx = (__bf16)xs[j];
                        ah[j] = hx;
                        al[j] = (__bf16)(xs[j] - (float)hx);
                    }
                    acc0 = __builtin_amdgcn_mfma_f32_16x16x32_bf16(ah, whf[ks][0], acc0, 0, 0, 0);
                    acc0 = __builtin_amdgcn_mfma_f32_16x16x32_bf16(ah, wlf[ks][0], acc0, 0, 0, 0);
                    acc0 = __builtin_amdgcn_mfma_f32_16x16x32_bf16(al, whf[ks][0], acc0, 0, 0, 0);
                    acc1 = __builtin_amdgcn_mfma_f32_16x16x32_bf16(ah, whf[ks][1], acc1, 0, 0, 0);
                    acc1 = __builtin_amdgcn_mfma_f32_16x16x32_bf16(ah, wlf[ks][1], acc1, 0, 0, 0);
                    acc1 = __builtin_amdgcn_mfma_f32_16x16x32_bf16(al, whf[ks][1], acc1, 0, 0, 0);
                }
#pragma unroll
                for (int j = 0; j < 4; ++j) {
                    const unsigned long long m0 = __ballot(acc0[j] > 0.f);
                    const unsigned long long m1 = __ballot(acc1[j] > 0.f);
                    if (m == 0) {
                        const unsigned int bits =
                            (unsigned int)((m0 >> (quad * 16)) & 0xFFFFull) |
                            ((unsigned int)((m1 >> (quad * 16)) & 0xFFFFull) << 16);
                        const long long gr = (long long)hb * 512 + c * 128
                                           + rbase + quad * 4 + j;
                        if (gr < NROWS) sig[gr] = bits;
                    }
                }
            }
        }
    }
}

// ---------------------------------------------------------------------------
// K_tf (R9): merged k_topk (blocks 0..2047) and k_featsqk (blocks
// 2048..2815: 512 feats blocks + 256 qk blocks). Independent workloads;
// both depend only on k_ph outputs.
// ---------------------------------------------------------------------------
__global__ __launch_bounds__(256) void k_tf(
    const float* __restrict__ oh_tab, const float* __restrict__ sp_tab,
    const float* __restrict__ hw,
    const unsigned int* __restrict__ sig,
    const int* __restrict__ oh_ids, const int* __restrict__ mh_ids,
    const int* __restrict__ sp_ids,
    int* __restrict__ sel,
    __bf16* __restrict__ feats,
    const float* __restrict__ Mq, const float* __restrict__ B1,
    float* __restrict__ qk_all)
{
    __shared__ __align__(16) int ism[1056];
    const int bid = blockIdx.x, t = threadIdx.x;

    if (bid < 2048) {
        // ---- top-K branch ----
        const int b = bid & 511, f = bid >> 9;
        const int lane = t & 63, wave = t >> 6;
        float* tgt = (float*)ism;                       // [64]
        unsigned int* thbits = (unsigned int*)&ism[64];
        int (*hist)[34] = (int(*)[34])&ism[65];         // [4][34]
        int* wtot = &ism[201];                          // [4]
        int* s_ds = &ism[205];
        int* s_cl = &ism[206];
        if (t < 64) tgt[t] = oh_tab[((size_t)f * VOH + oh_ids[b * 15 + f]) * 64 + t];
        if (t == 0) *thbits = 0u;
        if (t < 136) ((int*)hist)[t] = 0;
        __syncthreads();
        if (t < 32) {
            float acc = 0.f;
#pragma unroll
            for (int e = 0; e < 64; ++e) acc += tgt[e] * hw[e * 32 + t];
            if (acc > 0.f) atomicOr(thbits, 1u << t);
        }
        __syncthreads();
        const unsigned int th = *thbits;
        const int* idp = mh_ids + (size_t)(f * NB + b) * SEQ + t * 8;
        int ids[8], dv[8];
#pragma unroll
        for (int j = 0; j < 8; ++j) {
            int id = idp[j];
            ids[j] = id;
            int d = (id >= 0) ? __popc(sig[f * VMH + id] ^ th) : 33;
            dv[j] = d;
            atomicAdd(&hist[wave][d], 1);
        }
        __syncthreads();
        if (t == 0) {
            int cum = 0, ds = 33, cl = 0;
            for (int d = 0; d <= 33; ++d) {
                const int tot = hist[0][d] + hist[1][d] + hist[2][d] + hist[3][d];
                if (cum + tot >= TOPK) { ds = d; cl = cum; break; }
                cum += tot;
            }
            *s_ds = ds; *s_cl = cl;
        }
        __syncthreads();
        const int Dstar = *s_ds, cntlt = *s_cl;
        int nlt = 0, neq = 0;
#pragma unroll
        for (int j = 0; j < 8; ++j) {
            nlt += (dv[j] < Dstar);
            neq += (dv[j] == Dstar);
        }
        int scan = (nlt << 16) | neq;
#pragma unroll
        for (int off = 1; off < 64; off <<= 1) {
            const int u = __shfl_up(scan, off);
            if (lane >= off) scan += u;
        }
        if (lane == 63) wtot[wave] = scan;
        __syncthreads();
        int pre = 0;
        for (int w = 0; w < wave; ++w) pre += wtot[w];
        scan += pre;
        int lt_pos = (scan >> 16) - nlt;             // exclusive prefix of nlt
        int eq_pos = cntlt + (scan & 0xFFFF) - neq;  // exclusive prefix of neq
        int* selp = sel + (size_t)(f * NB + b) * TOPK;
#pragma unroll
        for (int j = 0; j < 8; ++j) {
            if (dv[j] < Dstar) { selp[lt_pos++] = ids[j]; }
            else if (dv[j] == Dstar) {
                if (eq_pos < TOPK) selp[eq_pos] = ids[j];
                eq_pos++;
            }
        }
    } else if (bid < 2048 + NB) {
        // ---- feats branch (oh rows + sp sum, ILP-unrolled gathers) ----
        const int b = bid - 2048;
        int* sidl = ism;            // [200]
        int* ohid = &ism[200];      // [15]
        if (t < 200) sidl[t] = sp_ids[(size_t)((t / 50) * NB + b) * 50 + (t % 50)];
        if (t >= 240 && t < 255) ohid[t - 240] = oh_ids[b * 15 + (t - 240)];
        __syncthreads();
        __bf16* fr = feats + (size_t)b * D0;
#pragma unroll
        for (int p = t; p < 960; p += 256) {
            int f = p >> 6, e = p & 63;
            fr[p] = (__bf16)oh_tab[((size_t)f * VOH + ohid[f]) * 64 + e];
        }
        {
            const int f = t >> 6, e = t & 63;
            const float* base = sp_tab + (size_t)f * VOH * 64 + e;
            const int* sp = &sidl[f * 50];
            float acc = 0.f;
#pragma unroll 10
            for (int j = 0; j < 50; ++j) {
                const int id = sp[j];
                const float v = base[(size_t)(id >= 0 ? id : 0) * 64];
                acc += (id >= 0) ? v : 0.f;
            }
            fr[960 + t] = (__bf16)acc;
        }
    } else {
        // ---- qk precompute branch (16 b's per block) ----
        const int idx = bid - 2048 - NB;               // 0..255
        const int bc = (idx & 31) * 16, f = (idx >> 5) & 3, z = idx >> 7;
        int* sid16 = ism;                              // [16]
        float (*tgt16)[64] = (float(*)[64])&ism[16];   // [16][64]
        if (t < 16) sid16[t] = oh_ids[(bc + t) * 15 + f];
        __syncthreads();
        {
            const int r = t >> 4, c4 = (t & 15) << 2;
            *(float4*)&tgt16[r][c4] =
                *(const float4*)&oh_tab[((size_t)f * VOH + sid16[r]) * 64 + c4];
        }
        __syncthreads();
        const int e = t & 63, bgrp = t >> 6;
        const int zf = z * 4 + f;
        const float* Mqb = Mq + (size_t)(zf * 4) * 4096;
        const float* B1b = B1 + zf * 4 * 64;
        float* op = qk_all + ((size_t)zf * 512 + bc) * 256;
#pragma unroll
        for (int h = 0; h < 4; ++h) {
            const float* mr = Mqb + h * 4096 + e;
            float a0 = 0.f, a1 = 0.f, a2 = 0.f, a3 = 0.f;
#pragma unroll
            for (int ep4 = 0; ep4 < 16; ++ep4) {
                const float m0 = mr[(ep4 * 4 + 0) * 64];
                const float m1 = mr[(ep4 * 4 + 1) * 64];
                const float m2 = mr[(ep4 * 4 + 2) * 64];
                const float m3 = mr[(ep4 * 4 + 3) * 64];
                const float4 t0 = *(const float4*)&tgt16[bgrp * 4 + 0][ep4 * 4];
                const float4 t1 = *(const float4*)&tgt16[bgrp * 4 + 1][ep4 * 4];
                const float4 t2 = *(const float4*)&tgt16[bgrp * 4 + 2][ep4 * 4];
                const float4 t3 = *(const float4*)&tgt16[bgrp * 4 + 3][ep4 * 4];
                a0 += t0.x * m0 + t0.y * m1 + t0.z * m2 + t0.w * m3;
                a1 += t1.x * m0 + t1.y * m1 + t1.z * m2 + t1.w * m3;
                a2 += t2.x * m0 + t2.y * m1 + t2.z * m2 + t2.w * m3;
                a3 += t3.x * m0 + t3.y * m1 + t3.z * m2 + t3.w * m3;
            }
            const float bb = B1b[h * 64 + e];
            op[(bgrp * 4 + 0) * 256 + h * 64 + e] = (a0 + bb) * RSQRT32;
            op[(bgrp * 4 + 1) * 256 + h * 64 + e] = (a1 + bb) * RSQRT32;
            op[(bgrp * 4 + 2) * 256 + h * 64 + e] = (a2 + bb) * RSQRT32;
            op[(bgrp * 4 + 3) * 256 + h * 64 + e] = (a3 + bb) * RSQRT32;
        }
    }
}

// ---------------------------------------------------------------------------
// K3: attention core only — gather seq, scores, softmax, weighted-emb.
// ---------------------------------------------------------------------------
__global__ __launch_bounds__(256, 4) void k_attn(const float* __restrict__ mh_tab,
                                                 const int* __restrict__ mh_ids,
                                                 const int* __restrict__ sel,
                                                 const float* __restrict__ qk_all,
                                                 float* __restrict__ wembg)
{
    const int b = blockIdx.x, f = blockIdx.y, z = blockIdx.z, t = threadIdx.x;
    const int zf = z * 4 + f;

    __shared__ float seq[128][65];
    __shared__ int   sid[128];
    __shared__ float qk[4][64];
    __shared__ float sc[4][128];

    if (t < 128) {
        int id;
        if (z == 0) id = mh_ids[(size_t)(f * NB + b) * SEQ + t];
        else        id = sel[(size_t)(f * NB + b) * TOPK + t];
        sid[t] = id;
    }
    __syncthreads();
    float4 g[8];
#pragma unroll
    for (int i = 0; i < 8; ++i) {
        const int v = t + i * 256;
        const int row = v >> 4, c4 = (v & 15) << 2;
        const int id = sid[row];
        g[i] = make_float4(0.f, 0.f, 0.f, 0.f);
        if (id >= 0) g[i] = *(const float4*)&mh_tab[((size_t)f * VMH + id) * 64 + c4];
    }
    ((float*)qk)[t] = qk_all[((size_t)zf * 512 + b) * 256 + t];
#pragma unroll
    for (int i = 0; i < 8; ++i) {
        const int v = t + i * 256;
        const int row = v >> 4, c4 = (v & 15) << 2;
        seq[row][c4 + 0] = g[i].x; seq[row][c4 + 1] = g[i].y;
        seq[row][c4 + 2] = g[i].z; seq[row][c4 + 3] = g[i].w;
    }
    __syncthreads();
#pragma unroll
    for (int rep = 0; rep < 2; ++rep) {
        const int idx = t + rep * 256;
        const int h = idx >> 7, s = idx & 127;
        float acc = 0.f;
#pragma unroll
        for (int e4 = 0; e4 < 16; ++e4) {
            const float4 q4 = *(const float4*)&qk[h][e4 * 4];
            acc += seq[s][e4 * 4 + 0] * q4.x + seq[s][e4 * 4 + 1] * q4.y
                 + seq[s][e4 * 4 + 2] * q4.z + seq[s][e4 * 4 + 3] * q4.w;
        }
        sc[h][s] = (sid[s] >= 0) ? acc : -INFINITY;
    }
    __syncthreads();
    {
        const int h = t >> 6, l = t & 63;
        float v0 = sc[h][l], v1 = sc[h][l + 64];
        float m = fmaxf(v0, v1);
        for (int off = 32; off; off >>= 1) m = fmaxf(m, __shfl_xor(m, off));
        float p0 = expf(v0 - m), p1 = expf(v1 - m);
        float ssum = p0 + p1;
        for (int off = 32; off; off >>= 1) ssum += __shfl_xor(ssum, off);
        float inv = 1.f / ssum;
        sc[h][l] = p0 * inv; sc[h][l + 64] = p1 * inv;
    }
    // wemb: same-wave reads of sc[h] (wave-synchronous, no barrier needed)
    {
        const int h = t >> 6, e = t & 63;
        float acc = 0.f;
#pragma unroll 8
        for (int s4 = 0; s4 < 32; ++s4) {
            const float4 a4 = *(const float4*)&sc[h][s4 * 4];
            acc += a4.x * seq[s4 * 4 + 0][e] + a4.y * seq[s4 * 4 + 1][e]
                 + a4.z * seq[s4 * 4 + 2][e] + a4.w * seq[s4 * 4 + 3][e];
        }
        wembg[((size_t)zf * 512 + b) * 256 + t] = acc;
    }
}

// ---------------------------------------------------------------------------
// K_wvo: out[b][o] = sum_{h,e} wemb[b][h*64+e] * VO[h][e][o] + bvo[o]
// ---------------------------------------------------------------------------
__global__ __launch_bounds__(256) void k_wvo(const float* __restrict__ wembg,
                                             const float* __restrict__ VO,
                                             const float* __restrict__ bvo,
                                             __bf16* __restrict__ feats)
{
    const int t = threadIdx.x;
    const int bc = blockIdx.x * 16, f = blockIdx.y, z = blockIdx.z;
    const int zf = z * 4 + f;
    __shared__ float wemb16[16][256];
    const float* src = wembg + ((size_t)zf * 512 + bc) * 256;
#pragma unroll
    for (int i = 0; i < 4; ++i) {
        const int v = t + i * 256;                 // float4 index 0..1023
        *(float4*)&wemb16[v >> 6][(v & 63) << 2] = *(const float4*)&src[v * 4];
    }
    __syncthreads();
    const int o = t & 63, bgrp = t >> 6;
    const float* VOb = VO + (size_t)zf * 4 * 4096;
    float a0 = 0.f, a1 = 0.f, a2 = 0.f, a3 = 0.f;
#pragma unroll
    for (int h = 0; h < 4; ++h) {
        const float* vr = VOb + h * 4096 + o;
#pragma unroll
        for (int e4 = 0; e4 < 16; ++e4) {
            const float v0 = vr[(e4 * 4 + 0) * 64];
            const float v1 = vr[(e4 * 4 + 1) * 64];
            const float v2 = vr[(e4 * 4 + 2) * 64];
            const float v3 = vr[(e4 * 4 + 3) * 64];
            const float4 w0 = *(const float4*)&wemb16[bgrp * 4 + 0][h * 64 + e4 * 4];
            const float4 w1 = *(const float4*)&wemb16[bgrp * 4 + 1][h * 64 + e4 * 4];
            const float4 w2 = *(const float4*)&wemb16[bgrp * 4 + 2][h * 64 + e4 * 4];
            const float4 w3 = *(const float4*)&wemb16[bgrp * 4 + 3][h * 64 + e4 * 4];
            a0 += w0.x * v0 + w0.y * v1 + w0.z * v2 + w0.w * v3;
            a1 += w1.x * v0 + w1.y * v1 + w1.z * v2 + w1.w * v3;
            a2 += w2.x * v0 + w2.y * v1 + w2.z * v2 + w2.w * v3;
            a3 += w3.x * v0 + w3.y * v1 + w3.z * v2 + w3.w * v3;
        }
    }
    const float bv = bvo[zf * 64 + o];
    const int col = (z ? 1472 : 1216) + f * 64 + o;
    feats[(size_t)(bc + bgrp * 4 + 0) * D0 + col] = (__bf16)(a0 + bv);
    feats[(size_t)(bc + bgrp * 4 + 1) * D0 + col] = (__bf16)(a1 + bv);
    feats[(size_t)(bc + bgrp * 4 + 2) * D0 + col] = (__bf16)(a2 + bv);
    feats[(size_t)(bc + bgrp * 4 + 3) * D0 + col] = (__bf16)(a3 + bv);
}

// ---------------------------------------------------------------------------
// K5b: bf16 MFMA GEMM. A [M,K] bf16 rm, BT [N,K] bf16 rm (pre-transposed),
// C = act(A@B + bias) as bf16 [M,N]. 64x64 tile, 4 waves = 2x2 of 32x32.
// ---------------------------------------------------------------------------
__global__ __launch_bounds__(256) void gemm_mfma(const __bf16* __restrict__ A,
                                                 const __bf16* __restrict__ BT,
                                                 const float* __restrict__ bias,
                                                 __bf16* __restrict__ C,
                                                 int M, int N, int K, int relu)
{
    __shared__ __bf16 As[64][72];
    __shared__ __bf16 Bs[64][72];
    const int t = threadIdx.x;
    const int n0 = blockIdx.x * 64, m0 = blockIdx.y * 64;
    const int wave = t >> 6, lane = t & 63;
    const int wm = (wave >> 1) * 32, wn = (wave & 1) * 32;
    const int row16 = lane & 15, quad = lane >> 4;
    f32x4 acc[2][2] = {};
    const int sr = t >> 3;
    const int sseg = (t & 7) * 8;
    for (int k0 = 0; k0 < K; k0 += 64) {
        bf16x8 av0 = *(const bf16x8*)&A[(size_t)(m0 + sr) * K + k0 + sseg];
        bf16x8 av1 = *(const bf16x8*)&A[(size_t)(m0 + sr + 32) * K + k0 + sseg];
        bf16x8 bv0 = *(const bf16x8*)&BT[(size_t)(n0 + sr) * K + k0 + sseg];
        bf16x8 bv1 = *(const bf16x8*)&BT[(size_t)(n0 + sr + 32) * K + k0 + sseg];
        __syncthreads();
        *(bf16x8*)&As[sr][sseg] = av0;
        *(bf16x8*)&As[sr + 32][sseg] = av1;
        *(bf16x8*)&Bs[sr][sseg] = bv0;
        *(bf16x8*)&Bs[sr + 32][sseg] = bv1;
        __syncthreads();
#pragma unroll
        for (int kk = 0; kk < 2; ++kk) {
            bf16x8 a0 = *(const bf16x8*)&As[wm + row16][kk * 32 + quad * 8];
            bf16x8 a1 = *(const bf16x8*)&As[wm + 16 + row16][kk * 32 + quad * 8];
            bf16x8 b0 = *(const bf16x8*)&Bs[wn + row16][kk * 32 + quad * 8];
            bf16x8 b1 = *(const bf16x8*)&Bs[wn + 16 + row16][kk * 32 + quad * 8];
            acc[0][0] = __builtin_amdgcn_mfma_f32_16x16x32_bf16(a0, b0, acc[0][0], 0, 0, 0);
            acc[0][1] = __builtin_amdgcn_mfma_f32_16x16x32_bf16(a0, b1, acc[0][1], 0, 0, 0);
            acc[1][0] = __builtin_amdgcn_mfma_f32_16x16x32_bf16(a1, b0, acc[1][0], 0, 0, 0);
            acc[1][1] = __builtin_amdgcn_mfma_f32_16x16x32_bf16(a1, b1, acc[1][1], 0, 0, 0);
        }
    }
#pragma unroll
    for (int i = 0; i < 2; ++i)
#pragma unroll
        for (int j = 0; j < 2; ++j) {
            const int col = n0 + wn + j * 16 + row16;
            const float bz = bias[col];
#pragma unroll
            for (int r = 0; r < 4; ++r) {
                const int rowm = m0 + wm + i * 16 + quad * 4 + r;
                float v = acc[i][j][r] + bz;
                if (relu) v = fmaxf(v, 0.f);
                C[(size_t)rowm * N + col] = (__bf16)v;
            }
        }
}

// ---------------------------------------------------------------------------
// K6: final 256-dot + bias + sigmoid (x2 bf16). One wave per batch row.
// ---------------------------------------------------------------------------
__global__ __launch_bounds__(256) void k_out(const __bf16* __restrict__ x2,
                                             const float* __restrict__ outW,
                                             const float* __restrict__ outb,
                                             float* __restrict__ out)
{
    const int t = threadIdx.x;
    const int wave = t >> 6, lane = t & 63;
    const int row = blockIdx.x * 4 + wave;
    bf16x4 xv = *(const bf16x4*)&x2[(size_t)row * 256 + lane * 4];
    const float4 wv = *(const float4*)&outW[lane * 4];
    float v = (float)xv[0] * wv.x + (float)xv[1] * wv.y
            + (float)xv[2] * wv.z + (float)xv[3] * wv.w;
    for (int off = 32; off; off >>= 1) v += __shfl_down(v, off);
    if (lane == 0) {
        float lg = v + outb[0];
        out[row] = 1.f / (1.f + expf(-lg));
        out[NB + row] = lg;
    }
}

// ---------------------------------------------------------------------------
extern "C" void kernel_launch(void* const* d_in, const int* in_sizes, int n_in,
                              void* d_out, int out_size, void* d_ws, size_t ws_size,
                              hipStream_t stream)
{
    const float* oh_tab = (const float*)d_in[0];
    const float* mh_tab = (const float*)d_in[1];
    const float* sp_tab = (const float*)d_in[2];
    const float* hw     = (const float*)d_in[3];
    const float* sqW = (const float*)d_in[4];  const float* sqb = (const float*)d_in[5];
    const float* skW = (const float*)d_in[6];  const float* skb = (const float*)d_in[7];
    const float* svW = (const float*)d_in[8];  const float* svb = (const float*)d_in[9];
    const float* soW = (const float*)d_in[10]; const float* sob = (const float*)d_in[11];
    const float* lqW = (const float*)d_in[12]; const float* lqb = (const float*)d_in[13];
    const float* lkW = (const float*)d_in[14]; const float* lkb = (const float*)d_in[15];
    const float* lvW = (const float*)d_in[16]; const float* lvb = (const float*)d_in[17];
    const float* loW = (const float*)d_in[18]; const float* lob = (const float*)d_in[19];
    const float* W0 = (const float*)d_in[20];  const float* b0 = (const float*)d_in[21];
    const float* W1 = (const float*)d_in[22];  const float* b1 = (const float*)d_in[23];
    const float* W2 = (const float*)d_in[24];  const float* b2 = (const float*)d_in[25];
    const float* outW = (const float*)d_in[26]; const float* outb = (const float*)d_in[27];
    const int* oh_ids = (const int*)d_in[28];
    const int* mh_ids = (const int*)d_in[29];
    const int* sp_ids = (const int*)d_in[30];
    (void)skb; (void)lkb;   // folded; per-head constant cancels in softmax

    char* ws = (char*)d_ws;
    unsigned int* sig = (unsigned int*)(ws + 0);            // 400128 * 4
    int*    sel   = (int*)   (ws + 1600512);                // 262144 * 4
    __bf16* feats = (__bf16*)(ws + 2649088);                // 884736 * 2
    __bf16* x0    = (__bf16*)(ws + 4418560);                // 524288 * 2
    __bf16* x1    = (__bf16*)(ws + 5467136);                // 262144 * 2
    __bf16* x2    = (__bf16*)(ws + 5991424);                // 131072 * 2
    __bf16* WT0   = (__bf16*)(ws + 6253568);                // 1769472 * 2
    __bf16* WT1   = (__bf16*)(ws + 9792512);                // 524288 * 2
    __bf16* WT2   = (__bf16*)(ws + 10841088);               // 131072 * 2
    float*  Mq    = (float*) (ws + 11103232);               // 131072 * 4
    float*  VO    = (float*) (ws + 11627520);               // 131072 * 4
    float*  B1    = (float*) (ws + 12151808);               // 2048 * 4
    float*  bvo   = (float*) (ws + 12160000);               // 512 * 4
    float*  qk_all= (float*) (ws + 12162048);               // 1048576 * 4
    float*  wembg = (float*) (ws + 16356352);               // 1048576 * 4
    // total ws usage: 20550656 bytes

    k_ph<<<3182, 256, 0, stream>>>(W0, W1, W2, WT0, WT1, WT2,
                                   sqW, sqb, skW, svW, svb, soW, sob,
                                   lqW, lqb, lkW, lvW, lvb, loW, lob,
                                   Mq, B1, VO, bvo,
                                   mh_tab, hw, sig);
    k_tf<<<2048 + NB + 256, 256, 0, stream>>>(oh_tab, sp_tab, hw, sig,
                                              oh_ids, mh_ids, sp_ids,
                                              sel, feats, Mq, B1, qk_all);
    k_attn<<<dim3(NB, F_MH, 2), 256, 0, stream>>>(mh_tab, mh_ids, sel, qk_all, wembg);
    k_wvo<<<dim3(32, F_MH, 2), 256, 0, stream>>>(wembg, VO, bvo, feats);
    gemm_mfma<<<dim3(16, 8), 256, 0, stream>>>(feats, WT0, b0, x0, 512, 1024, 1728, 1);
    gemm_mfma<<<dim3(8, 8), 256, 0, stream>>>(x0, WT1, b1, x1, 512, 512, 1024, 1);
    gemm_mfma<<<dim3(4, 8), 256, 0, stream>>>(x1, WT2, b2, x2, 512, 256, 512, 1);
    k_out<<<NB / 4, 256, 0, stream>>>(x2, outW, outb, (float*)d_out);
}

// Round 4
// 388.795 us; speedup vs baseline: 1.0808x; 1.0808x over previous
//
#include <hip/hip_runtime.h>
#include <math.h>

#define F_MH 4
#define NB   512
#define SEQ  2048
#define TOPK 128
#define EDIM 64
#define ADIM 128
#define VOH  10001
#define VMH  100001
#define NROWS (F_MH * VMH)   // 400004
#define D0   1728
#define RSQRT32 0.17677669529663687f

typedef __bf16 bf16x8 __attribute__((ext_vector_type(8)));
typedef __bf16 bf16x4 __attribute__((ext_vector_type(4)));
typedef float  f32x4  __attribute__((ext_vector_type(4)));

// ---------------------------------------------------------------------------
// K_ph (R10): weight transposes (0..2367) + attn-weight folding (2368..2399)
// + LSH hash (2400..3181) + target-hash precompute (3182..3309).
// th precompute hoists the per-(f,b) 32-bit target signature out of the
// 2048 latency-bound top-K blocks (identical summation order -> same bits).
// ---------------------------------------------------------------------------
__global__ __launch_bounds__(256) void k_ph(
    const float* __restrict__ W0x, const float* __restrict__ W1x, const float* __restrict__ W2x,
    __bf16* __restrict__ WT0, __bf16* __restrict__ WT1, __bf16* __restrict__ WT2,
    const float* __restrict__ sqW, const float* __restrict__ sqb,
    const float* __restrict__ skW,
    const float* __restrict__ svW, const float* __restrict__ svb,
    const float* __restrict__ soW, const float* __restrict__ sob,
    const float* __restrict__ lqW, const float* __restrict__ lqb,
    const float* __restrict__ lkW,
    const float* __restrict__ lvW, const float* __restrict__ lvb,
    const float* __restrict__ loW, const float* __restrict__ lob,
    float* __restrict__ Mq, float* __restrict__ B1,
    float* __restrict__ VO, float* __restrict__ bvo,
    const float* __restrict__ tab, const float* __restrict__ hw,
    unsigned int* __restrict__ sig,
    const float* __restrict__ oh_tab, const int* __restrict__ oh_ids,
    unsigned int* __restrict__ thall)
{
    __shared__ __align__(16) float smem[8704];   // 34816 B
    const int bid = blockIdx.x, t = threadIdx.x;

    if (bid < 2368) {
        // ---- transpose branch ----
        const float* W; __bf16* WT; int N, K, base, nbs;
        if (bid < 1728)      { W = W0x; WT = WT0; K = 1728; N = 1024; base = 0;    nbs = 5; }
        else if (bid < 2240) { W = W1x; WT = WT1; K = 1024; N = 512;  base = 1728; nbs = 4; }
        else                 { W = W2x; WT = WT2; K = 512;  N = 256;  base = 2240; nbs = 3; }
        const int lb = bid - base;
        const int n0 = (lb & ((1 << nbs) - 1)) * 32, k0 = (lb >> nbs) * 32;
        float (*tile)[33] = (float(*)[33])smem;
        const int c = t & 31, r = t >> 5;
#pragma unroll
        for (int i = 0; i < 4; ++i)
            tile[r + 8 * i][c] = W[(size_t)(k0 + r + 8 * i) * N + n0 + c];
        __syncthreads();
#pragma unroll
        for (int i = 0; i < 4; ++i)
            WT[(size_t)(n0 + r + 8 * i) * K + k0 + c] = (__bf16)tile[c][r + 8 * i];
    } else if (bid < 2400) {
        // ---- attn-weight fold branch ----
        const int idx = bid - 2368;
        const int f = idx & 3, z = (idx >> 2) & 1, h = idx >> 3;
        const float* WQ = (z ? lqW : sqW) + (size_t)f * 8192;
        const float* bq = (z ? lqb : sqb) + f * 128;
        const float* WK = (z ? lkW : skW) + (size_t)f * 8192;
        const float* WV = (z ? lvW : svW) + (size_t)f * 8192;
        const float* bv = (z ? lvb : svb) + f * 128;
        const float* WO = (z ? loW : soW) + (size_t)f * 8192;
        const float* bo = (z ? lob : sob) + f * 64;
        float (*wq)[33] = (float(*)[33])smem;
        float (*wk)[33] = (float(*)[33])(smem + 2112);
        float (*wv)[33] = (float(*)[33])(smem + 4224);
        float (*wo)[65] = (float(*)[65])(smem + 6336);
#pragma unroll
        for (int i = 0; i < 8; ++i) {
            int j = t + i * 256;
            wq[j >> 5][j & 31] = WQ[(j >> 5) * 128 + h * 32 + (j & 31)];
            wk[j >> 5][j & 31] = WK[(j >> 5) * 128 + h * 32 + (j & 31)];
            wv[j >> 5][j & 31] = WV[(j >> 5) * 128 + h * 32 + (j & 31)];
            wo[j >> 6][j & 63] = WO[(h * 32 + (j >> 6)) * 64 + (j & 63)];
        }
        __syncthreads();
        const int lane = t & 63, grp = t >> 6;
        float* Mqb = Mq + (size_t)(((z * 4 + f) * 4 + h)) * 4096;
        float* VOb = VO + (size_t)(((z * 4 + f) * 4 + h)) * 4096;
#pragma unroll 4
        for (int g = 0; g < 16; ++g) {
            const int ep = grp * 16 + g;
            float am = 0.f, av = 0.f;
#pragma unroll
            for (int d = 0; d < 32; ++d) {
                am += wq[ep][d] * wk[lane][d];
                av += wv[ep][d] * wo[d][lane];
            }
            Mqb[ep * 64 + lane] = am;
            VOb[ep * 64 + lane] = av;
        }
        if (t < 64) {
            float acc = 0.f;
#pragma unroll
            for (int d = 0; d < 32; ++d) acc += bq[h * 32 + d] * wk[t][d];
            B1[((z * 4 + f) * 4 + h) * 64 + t] = acc;
        }
        if (h == 0 && t >= 64 && t < 128) {
            const int o = t - 64;
            float acc = bo[o];
            for (int a = 0; a < 128; ++a) acc += bv[a] * WO[a * 64 + o];
            bvo[(z * 4 + f) * 64 + o] = acc;
        }
    } else if (bid < 3182) {
        // ---- LSH hash branch ----
        const int hb = bid - 2400;
        float (*rows)[68] = (float(*)[68])smem;   // pitch 68: 16B-aligned b128
        const int lane = t & 63, wave = t >> 6;
        const int m = lane & 15, quad = lane >> 4;

        bf16x8 whf[2][2], wlf[2][2];
#pragma unroll
        for (int ks = 0; ks < 2; ++ks)
#pragma unroll
            for (int hf = 0; hf < 2; ++hf) {
                bf16x8 bh, bl;
#pragma unroll
                for (int j = 0; j < 8; ++j) {
                    const float w = hw[(ks * 32 + quad * 8 + j) * 32 + hf * 16 + m];
                    const __bf16 h = (__bf16)w;
                    bh[j] = h;
                    bl[j] = (__bf16)(w - (float)h);
                }
                whf[ks][hf] = bh; wlf[ks][hf] = bl;
            }

        const long long base_dw = (long long)hb * 32768;   // 512 rows * 64
        const long long lim = (long long)NROWS * 64;
        float4 pf[8];
#pragma unroll
        for (int i = 0; i < 8; ++i) {
            const long long idx = base_dw + i * 1024 + t * 4;
            pf[i] = make_float4(0.f, 0.f, 0.f, 0.f);
            if (idx < lim) pf[i] = *(const float4*)(tab + idx);
        }
        for (int c = 0; c < 4; ++c) {
            __syncthreads();              // prior chunk's LDS reads done
#pragma unroll
            for (int i = 0; i < 8; ++i) {
                const int v = t + i * 256;              // float4 index 0..2047
                *(float4*)&rows[v >> 4][(v & 15) << 2] = pf[i];
            }
            __syncthreads();
            if (c < 3) {                  // prefetch next chunk under compute
#pragma unroll
                for (int i = 0; i < 8; ++i) {
                    const long long idx = base_dw + (long long)(c + 1) * 8192 + i * 1024 + t * 4;
                    pf[i] = make_float4(0.f, 0.f, 0.f, 0.f);
                    if (idx < lim) pf[i] = *(const float4*)(tab + idx);
                }
            }
#pragma unroll
            for (int tile = 0; tile < 2; ++tile) {
                const int rbase = wave * 32 + tile * 16;
                f32x4 acc0 = {0.f, 0.f, 0.f, 0.f}, acc1 = {0.f, 0.f, 0.f, 0.f};
#pragma unroll
                for (int ks = 0; ks < 2; ++ks) {
                    const float* src = &rows[rbase + m][ks * 32 + quad * 8];
                    const float4 x0 = *(const float4*)(src);
                    const float4 x1 = *(const float4*)(src + 4);
                    float xs[8] = {x0.x, x0.y, x0.z, x0.w, x1.x, x1.y, x1.z, x1.w};
                    bf16x8 ah, al;
#pragma unroll
                    for (int j = 0; j < 8; ++j) {
                        const __bf16 hx = (__bf16)xs[j];
                        ah[j] = hx;
                        al[j] = (__bf16)(xs[j] - (float)hx);
                    }
                    acc0 = __builtin_amdgcn_mfma_f32_16x16x32_bf16(ah, whf[ks][0], acc0, 0, 0, 0);
                    acc0 = __builtin_amdgcn_mfma_f32_16x16x32_bf16(ah, wlf[ks][0], acc0, 0, 0, 0);
                    acc0 = __builtin_amdgcn_mfma_f32_16x16x32_bf16(al, whf[ks][0], acc0, 0, 0, 0);
                    acc1 = __builtin_amdgcn_mfma_f32_16x16x32_bf16(ah, whf[ks][1], acc1, 0, 0, 0);
                    acc1 = __builtin_amdgcn_mfma_f32_16x16x32_bf16(ah, wlf[ks][1], acc1, 0, 0, 0);
                    acc1 = __builtin_amdgcn_mfma_f32_16x16x32_bf16(al, whf[ks][1], acc1, 0, 0, 0);
                }
#pragma unroll
                for (int j = 0; j < 4; ++j) {
                    const unsigned long long m0 = __ballot(acc0[j] > 0.f);
                    const unsigned long long m1 = __ballot(acc1[j] > 0.f);
                    if (m == 0) {
                        const unsigned int bits =
                            (unsigned int)((m0 >> (quad * 16)) & 0xFFFFull) |
                            ((unsigned int)((m1 >> (quad * 16)) & 0xFFFFull) << 16);
                        const long long gr = (long long)hb * 512 + c * 128
                                           + rbase + quad * 4 + j;
                        if (gr < NROWS) sig[gr] = bits;
                    }
                }
            }
        }
    } else {
        // ---- target-hash precompute: 16 (f,b) pairs per block ----
        const int pb = (bid - 3182) * 16;          // global pair base
        const int f = pb >> 9, b0 = pb & 511;      // same f for whole block
        int* sid16 = (int*)smem;                   // [16]
        float (*tgt16)[64] = (float(*)[64])(smem + 16);
        if (t < 16) sid16[t] = oh_ids[(b0 + t) * 15 + f];
        __syncthreads();
        {
            const int r = t >> 4, c4 = (t & 15) << 2;
            *(float4*)&tgt16[r][c4] =
                *(const float4*)&oh_tab[((size_t)f * VOH + sid16[r]) * 64 + c4];
        }
        __syncthreads();
        const int lane = t & 63;
        const int bit = lane & 31;
#pragma unroll
        for (int it = 0; it < 2; ++it) {
            const int pl = (t >> 5) + it * 8;      // pair_local 0..15
            const float* tg = tgt16[pl];
            float acc = 0.f;
#pragma unroll
            for (int e = 0; e < 64; ++e) acc += tg[e] * hw[e * 32 + bit];
            const unsigned long long mm = __ballot(acc > 0.f);
            if (lane == 0)  thall[pb + pl] = (unsigned int)(mm & 0xFFFFFFFFull);
            if (lane == 32) thall[pb + pl] = (unsigned int)(mm >> 32);
        }
    }
}

// ---------------------------------------------------------------------------
// K2 (R10): standalone top-K, occupancy-first. Low VGPR (launch_bounds 256,8),
// th precomputed, int4 id loads, unconditional clamped sig gathers (8 in
// flight), histogram atomics after all distances resolve.
// ---------------------------------------------------------------------------
__global__ __launch_bounds__(256, 8) void k_topk(
    const unsigned int* __restrict__ sig,
    const unsigned int* __restrict__ thall,
    const int* __restrict__ mh_ids,
    int* __restrict__ sel)
{
    const int b = blockIdx.x, f = blockIdx.y, t = threadIdx.x;
    const int lane = t & 63, wave = t >> 6;
    __shared__ int hist[4][34];
    __shared__ int wtot[4];
    __shared__ int s_dstar, s_cntlt;
    if (t < 136) ((int*)hist)[t] = 0;
    const unsigned int th = thall[f * NB + b];
    const int* idp = mh_ids + (size_t)(f * NB + b) * SEQ + t * 8;
    const int4 iv0 = *(const int4*)idp;
    const int4 iv1 = *(const int4*)(idp + 4);
    const int ids[8] = {iv0.x, iv0.y, iv0.z, iv0.w, iv1.x, iv1.y, iv1.z, iv1.w};
    int dv[8];
    const unsigned int* sb = sig + f * VMH;
#pragma unroll
    for (int j = 0; j < 8; ++j) {
        const int id = ids[j];
        const unsigned int s = sb[id >= 0 ? id : 0];
        dv[j] = (id >= 0) ? __popc(s ^ th) : 33;
    }
    __syncthreads();            // hist zero-init visible
#pragma unroll
    for (int j = 0; j < 8; ++j) atomicAdd(&hist[wave][dv[j]], 1);
    __syncthreads();
    if (t == 0) {
        int cum = 0, ds = 33, cl = 0;
        for (int d = 0; d <= 33; ++d) {
            const int tot = hist[0][d] + hist[1][d] + hist[2][d] + hist[3][d];
            if (cum + tot >= TOPK) { ds = d; cl = cum; break; }
            cum += tot;
        }
        s_dstar = ds; s_cntlt = cl;
    }
    __syncthreads();
    const int Dstar = s_dstar, cntlt = s_cntlt;
    int nlt = 0, neq = 0;
#pragma unroll
    for (int j = 0; j < 8; ++j) {
        nlt += (dv[j] < Dstar);
        neq += (dv[j] == Dstar);
    }
    // packed (nlt<<16 | neq) inclusive scan: wave shuffle + cross-wave totals
    int scan = (nlt << 16) | neq;
#pragma unroll
    for (int off = 1; off < 64; off <<= 1) {
        const int u = __shfl_up(scan, off);
        if (lane >= off) scan += u;
    }
    if (lane == 63) wtot[wave] = scan;
    __syncthreads();
    int pre = 0;
    for (int w = 0; w < wave; ++w) pre += wtot[w];
    scan += pre;
    int lt_pos = (scan >> 16) - nlt;             // exclusive prefix of nlt
    int eq_pos = cntlt + (scan & 0xFFFF) - neq;  // exclusive prefix of neq
    int* selp = sel + (size_t)(f * NB + b) * TOPK;
#pragma unroll
    for (int j = 0; j < 8; ++j) {
        if (dv[j] < Dstar) { selp[lt_pos++] = ids[j]; }
        else if (dv[j] == Dstar) {
            if (eq_pos < TOPK) selp[eq_pos] = ids[j];
            eq_pos++;
        }
    }
}

// ---------------------------------------------------------------------------
// K_fq (R10): feats assembly (blocks 0..NB-1) + qk precompute (NB..NB+255).
// Same VGPR class in both branches; ILP-unrolled gathers.
// ---------------------------------------------------------------------------
__global__ __launch_bounds__(256) void k_fq(
    const float* __restrict__ oh_tab, const float* __restrict__ sp_tab,
    const int* __restrict__ oh_ids, const int* __restrict__ sp_ids,
    __bf16* __restrict__ feats,
    const float* __restrict__ Mq, const float* __restrict__ B1,
    float* __restrict__ qk_all)
{
    __shared__ __align__(16) int ism[1056];
    const int bid = blockIdx.x, t = threadIdx.x;

    if (bid < NB) {
        // ---- feats branch (oh rows + sp sum) ----
        const int b = bid;
        int* sidl = ism;            // [200]
        int* ohid = &ism[200];      // [15]
        if (t < 200) sidl[t] = sp_ids[(size_t)((t / 50) * NB + b) * 50 + (t % 50)];
        if (t >= 240 && t < 255) ohid[t - 240] = oh_ids[b * 15 + (t - 240)];
        __syncthreads();
        __bf16* fr = feats + (size_t)b * D0;
#pragma unroll
        for (int p = t; p < 960; p += 256) {
            int f = p >> 6, e = p & 63;
            fr[p] = (__bf16)oh_tab[((size_t)f * VOH + ohid[f]) * 64 + e];
        }
        {
            const int f = t >> 6, e = t & 63;
            const float* base = sp_tab + (size_t)f * VOH * 64 + e;
            const int* sp = &sidl[f * 50];
            float acc = 0.f;
#pragma unroll 10
            for (int j = 0; j < 50; ++j) {
                const int id = sp[j];
                const float v = base[(size_t)(id >= 0 ? id : 0) * 64];
                acc += (id >= 0) ? v : 0.f;
            }
            fr[960 + t] = (__bf16)acc;
        }
    } else {
        // ---- qk precompute branch (16 b's per block) ----
        const int idx = bid - NB;                      // 0..255
        const int bc = (idx & 31) * 16, f = (idx >> 5) & 3, z = idx >> 7;
        int* sid16 = ism;                              // [16]
        float (*tgt16)[64] = (float(*)[64])&ism[16];   // [16][64]
        if (t < 16) sid16[t] = oh_ids[(bc + t) * 15 + f];
        __syncthreads();
        {
            const int r = t >> 4, c4 = (t & 15) << 2;
            *(float4*)&tgt16[r][c4] =
                *(const float4*)&oh_tab[((size_t)f * VOH + sid16[r]) * 64 + c4];
        }
        __syncthreads();
        const int e = t & 63, bgrp = t >> 6;
        const int zf = z * 4 + f;
        const float* Mqb = Mq + (size_t)(zf * 4) * 4096;
        const float* B1b = B1 + zf * 4 * 64;
        float* op = qk_all + ((size_t)zf * 512 + bc) * 256;
#pragma unroll
        for (int h = 0; h < 4; ++h) {
            const float* mr = Mqb + h * 4096 + e;
            float a0 = 0.f, a1 = 0.f, a2 = 0.f, a3 = 0.f;
#pragma unroll
            for (int ep4 = 0; ep4 < 16; ++ep4) {
                const float m0 = mr[(ep4 * 4 + 0) * 64];
                const float m1 = mr[(ep4 * 4 + 1) * 64];
                const float m2 = mr[(ep4 * 4 + 2) * 64];
                const float m3 = mr[(ep4 * 4 + 3) * 64];
                const float4 t0 = *(const float4*)&tgt16[bgrp * 4 + 0][ep4 * 4];
                const float4 t1 = *(const float4*)&tgt16[bgrp * 4 + 1][ep4 * 4];
                const float4 t2 = *(const float4*)&tgt16[bgrp * 4 + 2][ep4 * 4];
                const float4 t3 = *(const float4*)&tgt16[bgrp * 4 + 3][ep4 * 4];
                a0 += t0.x * m0 + t0.y * m1 + t0.z * m2 + t0.w * m3;
                a1 += t1.x * m0 + t1.y * m1 + t1.z * m2 + t1.w * m3;
                a2 += t2.x * m0 + t2.y * m1 + t2.z * m2 + t2.w * m3;
                a3 += t3.x * m0 + t3.y * m1 + t3.z * m2 + t3.w * m3;
            }
            const float bb = B1b[h * 64 + e];
            op[(bgrp * 4 + 0) * 256 + h * 64 + e] = (a0 + bb) * RSQRT32;
            op[(bgrp * 4 + 1) * 256 + h * 64 + e] = (a1 + bb) * RSQRT32;
            op[(bgrp * 4 + 2) * 256 + h * 64 + e] = (a2 + bb) * RSQRT32;
            op[(bgrp * 4 + 3) * 256 + h * 64 + e] = (a3 + bb) * RSQRT32;
        }
    }
}

// ---------------------------------------------------------------------------
// K3: attention core only — gather seq, scores, softmax, weighted-emb.
// ---------------------------------------------------------------------------
__global__ __launch_bounds__(256, 4) void k_attn(const float* __restrict__ mh_tab,
                                                 const int* __restrict__ mh_ids,
                                                 const int* __restrict__ sel,
                                                 const float* __restrict__ qk_all,
                                                 float* __restrict__ wembg)
{
    const int b = blockIdx.x, f = blockIdx.y, z = blockIdx.z, t = threadIdx.x;
    const int zf = z * 4 + f;

    __shared__ float seq[128][65];
    __shared__ int   sid[128];
    __shared__ float qk[4][64];
    __shared__ float sc[4][128];

    if (t < 128) {
        int id;
        if (z == 0) id = mh_ids[(size_t)(f * NB + b) * SEQ + t];
        else        id = sel[(size_t)(f * NB + b) * TOPK + t];
        sid[t] = id;
    }
    __syncthreads();
    float4 g[8];
#pragma unroll
    for (int i = 0; i < 8; ++i) {
        const int v = t + i * 256;
        const int row = v >> 4, c4 = (v & 15) << 2;
        const int id = sid[row];
        g[i] = make_float4(0.f, 0.f, 0.f, 0.f);
        if (id >= 0) g[i] = *(const float4*)&mh_tab[((size_t)f * VMH + id) * 64 + c4];
    }
    ((float*)qk)[t] = qk_all[((size_t)zf * 512 + b) * 256 + t];
#pragma unroll
    for (int i = 0; i < 8; ++i) {
        const int v = t + i * 256;
        const int row = v >> 4, c4 = (v & 15) << 2;
        seq[row][c4 + 0] = g[i].x; seq[row][c4 + 1] = g[i].y;
        seq[row][c4 + 2] = g[i].z; seq[row][c4 + 3] = g[i].w;
    }
    __syncthreads();
#pragma unroll
    for (int rep = 0; rep < 2; ++rep) {
        const int idx = t + rep * 256;
        const int h = idx >> 7, s = idx & 127;
        float acc = 0.f;
#pragma unroll
        for (int e4 = 0; e4 < 16; ++e4) {
            const float4 q4 = *(const float4*)&qk[h][e4 * 4];
            acc += seq[s][e4 * 4 + 0] * q4.x + seq[s][e4 * 4 + 1] * q4.y
                 + seq[s][e4 * 4 + 2] * q4.z + seq[s][e4 * 4 + 3] * q4.w;
        }
        sc[h][s] = (sid[s] >= 0) ? acc : -INFINITY;
    }
    __syncthreads();
    {
        const int h = t >> 6, l = t & 63;
        float v0 = sc[h][l], v1 = sc[h][l + 64];
        float m = fmaxf(v0, v1);
        for (int off = 32; off; off >>= 1) m = fmaxf(m, __shfl_xor(m, off));
        float p0 = expf(v0 - m), p1 = expf(v1 - m);
        float ssum = p0 + p1;
        for (int off = 32; off; off >>= 1) ssum += __shfl_xor(ssum, off);
        float inv = 1.f / ssum;
        sc[h][l] = p0 * inv; sc[h][l + 64] = p1 * inv;
    }
    // wemb: same-wave reads of sc[h] (wave-synchronous, no barrier needed)
    {
        const int h = t >> 6, e = t & 63;
        float acc = 0.f;
#pragma unroll 8
        for (int s4 = 0; s4 < 32; ++s4) {
            const float4 a4 = *(const float4*)&sc[h][s4 * 4];
            acc += a4.x * seq[s4 * 4 + 0][e] + a4.y * seq[s4 * 4 + 1][e]
                 + a4.z * seq[s4 * 4 + 2][e] + a4.w * seq[s4 * 4 + 3][e];
        }
        wembg[((size_t)zf * 512 + b) * 256 + t] = acc;
    }
}

// ---------------------------------------------------------------------------
// K_wvo: out[b][o] = sum_{h,e} wemb[b][h*64+e] * VO[h][e][o] + bvo[o]
// ---------------------------------------------------------------------------
__global__ __launch_bounds__(256) void k_wvo(const float* __restrict__ wembg,
                                             const float* __restrict__ VO,
                                             const float* __restrict__ bvo,
                                             __bf16* __restrict__ feats)
{
    const int t = threadIdx.x;
    const int bc = blockIdx.x * 16, f = blockIdx.y, z = blockIdx.z;
    const int zf = z * 4 + f;
    __shared__ float wemb16[16][256];
    const float* src = wembg + ((size_t)zf * 512 + bc) * 256;
#pragma unroll
    for (int i = 0; i < 4; ++i) {
        const int v = t + i * 256;                 // float4 index 0..1023
        *(float4*)&wemb16[v >> 6][(v & 63) << 2] = *(const float4*)&src[v * 4];
    }
    __syncthreads();
    const int o = t & 63, bgrp = t >> 6;
    const float* VOb = VO + (size_t)zf * 4 * 4096;
    float a0 = 0.f, a1 = 0.f, a2 = 0.f, a3 = 0.f;
#pragma unroll
    for (int h = 0; h < 4; ++h) {
        const float* vr = VOb + h * 4096 + o;
#pragma unroll
        for (int e4 = 0; e4 < 16; ++e4) {
            const float v0 = vr[(e4 * 4 + 0) * 64];
            const float v1 = vr[(e4 * 4 + 1) * 64];
            const float v2 = vr[(e4 * 4 + 2) * 64];
            const float v3 = vr[(e4 * 4 + 3) * 64];
            const float4 w0 = *(const float4*)&wemb16[bgrp * 4 + 0][h * 64 + e4 * 4];
            const float4 w1 = *(const float4*)&wemb16[bgrp * 4 + 1][h * 64 + e4 * 4];
            const float4 w2 = *(const float4*)&wemb16[bgrp * 4 + 2][h * 64 + e4 * 4];
            const float4 w3 = *(const float4*)&wemb16[bgrp * 4 + 3][h * 64 + e4 * 4];
            a0 += w0.x * v0 + w0.y * v1 + w0.z * v2 + w0.w * v3;
            a1 += w1.x * v0 + w1.y * v1 + w1.z * v2 + w1.w * v3;
            a2 += w2.x * v0 + w2.y * v1 + w2.z * v2 + w2.w * v3;
            a3 += w3.x * v0 + w3.y * v1 + w3.z * v2 + w3.w * v3;
        }
    }
    const float bv = bvo[zf * 64 + o];
    const int col = (z ? 1472 : 1216) + f * 64 + o;
    feats[(size_t)(bc + bgrp * 4 + 0) * D0 + col] = (__bf16)(a0 + bv);
    feats[(size_t)(bc + bgrp * 4 + 1) * D0 + col] = (__bf16)(a1 + bv);
    feats[(size_t)(bc + bgrp * 4 + 2) * D0 + col] = (__bf16)(a2 + bv);
    feats[(size_t)(bc + bgrp * 4 + 3) * D0 + col] = (__bf16)(a3 + bv);
}

// ---------------------------------------------------------------------------
// K5b: bf16 MFMA GEMM. A [M,K] bf16 rm, BT [N,K] bf16 rm (pre-transposed),
// C = act(A@B + bias) as bf16 [M,N]. 64x64 tile, 4 waves = 2x2 of 32x32.
// ---------------------------------------------------------------------------
__global__ __launch_bounds__(256) void gemm_mfma(const __bf16* __restrict__ A,
                                                 const __bf16* __restrict__ BT,
                                                 const float* __restrict__ bias,
                                                 __bf16* __restrict__ C,
                                                 int M, int N, int K, int relu)
{
    __shared__ __bf16 As[64][72];
    __shared__ __bf16 Bs[64][72];
    const int t = threadIdx.x;
    const int n0 = blockIdx.x * 64, m0 = blockIdx.y * 64;
    const int wave = t >> 6, lane = t & 63;
    const int wm = (wave >> 1) * 32, wn = (wave & 1) * 32;
    const int row16 = lane & 15, quad = lane >> 4;
    f32x4 acc[2][2] = {};
    const int sr = t >> 3;
    const int sseg = (t & 7) * 8;
    for (int k0 = 0; k0 < K; k0 += 64) {
        bf16x8 av0 = *(const bf16x8*)&A[(size_t)(m0 + sr) * K + k0 + sseg];
        bf16x8 av1 = *(const bf16x8*)&A[(size_t)(m0 + sr + 32) * K + k0 + sseg];
        bf16x8 bv0 = *(const bf16x8*)&BT[(size_t)(n0 + sr) * K + k0 + sseg];
        bf16x8 bv1 = *(const bf16x8*)&BT[(size_t)(n0 + sr + 32) * K + k0 + sseg];
        __syncthreads();
        *(bf16x8*)&As[sr][sseg] = av0;
        *(bf16x8*)&As[sr + 32][sseg] = av1;
        *(bf16x8*)&Bs[sr][sseg] = bv0;
        *(bf16x8*)&Bs[sr + 32][sseg] = bv1;
        __syncthreads();
#pragma unroll
        for (int kk = 0; kk < 2; ++kk) {
            bf16x8 a0 = *(const bf16x8*)&As[wm + row16][kk * 32 + quad * 8];
            bf16x8 a1 = *(const bf16x8*)&As[wm + 16 + row16][kk * 32 + quad * 8];
            bf16x8 b0 = *(const bf16x8*)&Bs[wn + row16][kk * 32 + quad * 8];
            bf16x8 b1 = *(const bf16x8*)&Bs[wn + 16 + row16][kk * 32 + quad * 8];
            acc[0][0] = __builtin_amdgcn_mfma_f32_16x16x32_bf16(a0, b0, acc[0][0], 0, 0, 0);
            acc[0][1] = __builtin_amdgcn_mfma_f32_16x16x32_bf16(a0, b1, acc[0][1], 0, 0, 0);
            acc[1][0] = __builtin_amdgcn_mfma_f32_16x16x32_bf16(a1, b0, acc[1][0], 0, 0, 0);
            acc[1][1] = __builtin_amdgcn_mfma_f32_16x16x32_bf16(a1, b1, acc[1][1], 0, 0, 0);
        }
    }
#pragma unroll
    for (int i = 0; i < 2; ++i)
#pragma unroll
        for (int j = 0; j < 2; ++j) {
            const int col = n0 + wn + j * 16 + row16;
            const float bz = bias[col];
#pragma unroll
            for (int r = 0; r < 4; ++r) {
                const int rowm = m0 + wm + i * 16 + quad * 4 + r;
                float v = acc[i][j][r] + bz;
                if (relu) v = fmaxf(v, 0.f);
                C[(size_t)rowm * N + col] = (__bf16)v;
            }
        }
}

// ---------------------------------------------------------------------------
// K6: final 256-dot + bias + sigmoid (x2 bf16). One wave per batch row.
// ---------------------------------------------------------------------------
__global__ __launch_bounds__(256) void k_out(const __bf16* __restrict__ x2,
                                             const float* __restrict__ outW,
                                             const float* __restrict__ outb,
                                             float* __restrict__ out)
{
    const int t = threadIdx.x;
    const int wave = t >> 6, lane = t & 63;
    const int row = blockIdx.x * 4 + wave;
    bf16x4 xv = *(const bf16x4*)&x2[(size_t)row * 256 + lane * 4];
    const float4 wv = *(const float4*)&outW[lane * 4];
    float v = (float)xv[0] * wv.x + (float)xv[1] * wv.y
            + (float)xv[2] * wv.z + (float)xv[3] * wv.w;
    for (int off = 32; off; off >>= 1) v += __shfl_down(v, off);
    if (lane == 0) {
        float lg = v + outb[0];
        out[row] = 1.f / (1.f + expf(-lg));
        out[NB + row] = lg;
    }
}

// ---------------------------------------------------------------------------
extern "C" void kernel_launch(void* const* d_in, const int* in_sizes, int n_in,
                              void* d_out, int out_size, void* d_ws, size_t ws_size,
                              hipStream_t stream)
{
    const float* oh_tab = (const float*)d_in[0];
    const float* mh_tab = (const float*)d_in[1];
    const float* sp_tab = (const float*)d_in[2];
    const float* hw     = (const float*)d_in[3];
    const float* sqW = (const float*)d_in[4];  const float* sqb = (const float*)d_in[5];
    const float* skW = (const float*)d_in[6];  const float* skb = (const float*)d_in[7];
    const float* svW = (const float*)d_in[8];  const float* svb = (const float*)d_in[9];
    const float* soW = (const float*)d_in[10]; const float* sob = (const float*)d_in[11];
    const float* lqW = (const float*)d_in[12]; const float* lqb = (const float*)d_in[13];
    const float* lkW = (const float*)d_in[14]; const float* lkb = (const float*)d_in[15];
    const float* lvW = (const float*)d_in[16]; const float* lvb = (const float*)d_in[17];
    const float* loW = (const float*)d_in[18]; const float* lob = (const float*)d_in[19];
    const float* W0 = (const float*)d_in[20];  const float* b0 = (const float*)d_in[21];
    const float* W1 = (const float*)d_in[22];  const float* b1 = (const float*)d_in[23];
    const float* W2 = (const float*)d_in[24];  const float* b2 = (const float*)d_in[25];
    const float* outW = (const float*)d_in[26]; const float* outb = (const float*)d_in[27];
    const int* oh_ids = (const int*)d_in[28];
    const int* mh_ids = (const int*)d_in[29];
    const int* sp_ids = (const int*)d_in[30];
    (void)skb; (void)lkb;   // folded; per-head constant cancels in softmax

    char* ws = (char*)d_ws;
    unsigned int* sig = (unsigned int*)(ws + 0);            // 400128 * 4
    int*    sel   = (int*)   (ws + 1600512);                // 262144 * 4
    __bf16* feats = (__bf16*)(ws + 2649088);                // 884736 * 2
    __bf16* x0    = (__bf16*)(ws + 4418560);                // 524288 * 2
    __bf16* x1    = (__bf16*)(ws + 5467136);                // 262144 * 2
    __bf16* x2    = (__bf16*)(ws + 5991424);                // 131072 * 2
    __bf16* WT0   = (__bf16*)(ws + 6253568);                // 1769472 * 2
    __bf16* WT1   = (__bf16*)(ws + 9792512);                // 524288 * 2
    __bf16* WT2   = (__bf16*)(ws + 10841088);               // 131072 * 2
    float*  Mq    = (float*) (ws + 11103232);               // 131072 * 4
    float*  VO    = (float*) (ws + 11627520);               // 131072 * 4
    float*  B1    = (float*) (ws + 12151808);               // 2048 * 4
    float*  bvo   = (float*) (ws + 12160000);               // 512 * 4
    float*  qk_all= (float*) (ws + 12162048);               // 1048576 * 4
    float*  wembg = (float*) (ws + 16356352);               // 1048576 * 4
    unsigned int* thall = (unsigned int*)(ws + 20550656);   // 2048 * 4
    // total ws usage: 20558848 bytes

    k_ph<<<3310, 256, 0, stream>>>(W0, W1, W2, WT0, WT1, WT2,
                                   sqW, sqb, skW, svW, svb, soW, sob,
                                   lqW, lqb, lkW, lvW, lvb, loW, lob,
                                   Mq, B1, VO, bvo,
                                   mh_tab, hw, sig,
                                   oh_tab, oh_ids, thall);
    k_topk<<<dim3(NB, F_MH), 256, 0, stream>>>(sig, thall, mh_ids, sel);
    k_fq<<<NB + 256, 256, 0, stream>>>(oh_tab, sp_tab, oh_ids, sp_ids,
                                       feats, Mq, B1, qk_all);
    k_attn<<<dim3(NB, F_MH, 2), 256, 0, stream>>>(mh_tab, mh_ids, sel, qk_all, wembg);
    k_wvo<<<dim3(32, F_MH, 2), 256, 0, stream>>>(wembg, VO, bvo, feats);
    gemm_mfma<<<dim3(16, 8), 256, 0, stream>>>(feats, WT0, b0, x0, 512, 1024, 1728, 1);
    gemm_mfma<<<dim3(8, 8), 256, 0, stream>>>(x0, WT1, b1, x1, 512, 512, 1024, 1);
    gemm_mfma<<<dim3(4, 8), 256, 0, stream>>>(x1, WT2, b2, x2, 512, 256, 512, 1);
    k_out<<<NB / 4, 256, 0, stream>>>(x2, outW, outb, (float*)d_out);
}

// Round 5
// 368.420 us; speedup vs baseline: 1.1405x; 1.0553x over previous
//
#include <hip/hip_runtime.h>
#include <math.h>

#define F_MH 4
#define NB   512
#define SEQ  2048
#define TOPK 128
#define EDIM 64
#define ADIM 128
#define VOH  10001
#define VMH  100001
#define NROWS (F_MH * VMH)   // 400004
#define D0   1728
#define RSQRT32 0.17677669529663687f

typedef __bf16 bf16x8 __attribute__((ext_vector_type(8)));
typedef __bf16 bf16x4 __attribute__((ext_vector_type(4)));
typedef float  f32x4  __attribute__((ext_vector_type(4)));

// ---------------------------------------------------------------------------
// K_ph (R11): one launch for all precompute, ordered longest-first:
//   bid    0..781  : LSH hash (bf16 hi/lo split MFMA)       [BW+MFMA]
//   bid  782..3149 : MLP weight transposes f32->bf16^T      [BW]
//   bid 3150..3181 : attn-weight folding (VO, bvo only)     [small]
//   bid 3182..3309 : target-hash precompute (th bits)       [small]
//   bid 3310..3821 : feats assembly (oh rows + sp sum)      [latency]
//   bid 3822..4077 : qk precompute, DIRECT (bq+tgt*WQ)*WK^T [latency]
// R11: qk no longer needs the Mq/B1 fold (dependency removed) -> k_fq merged
// here; latency-bound gather blocks overlap BW-bound hash/transpose blocks.
// ---------------------------------------------------------------------------
__global__ __launch_bounds__(256) void k_ph(
    const float* __restrict__ W0x, const float* __restrict__ W1x, const float* __restrict__ W2x,
    __bf16* __restrict__ WT0, __bf16* __restrict__ WT1, __bf16* __restrict__ WT2,
    const float* __restrict__ sqW, const float* __restrict__ sqb,
    const float* __restrict__ skW,
    const float* __restrict__ svW, const float* __restrict__ svb,
    const float* __restrict__ soW, const float* __restrict__ sob,
    const float* __restrict__ lqW, const float* __restrict__ lqb,
    const float* __restrict__ lkW,
    const float* __restrict__ lvW, const float* __restrict__ lvb,
    const float* __restrict__ loW, const float* __restrict__ lob,
    float* __restrict__ VO, float* __restrict__ bvo,
    const float* __restrict__ tab, const float* __restrict__ hw,
    unsigned int* __restrict__ sig,
    const float* __restrict__ oh_tab, const int* __restrict__ oh_ids,
    unsigned int* __restrict__ thall,
    const float* __restrict__ sp_tab, const int* __restrict__ sp_ids,
    __bf16* __restrict__ feats, float* __restrict__ qk_all)
{
    __shared__ __align__(16) float smem[8704];   // 34816 B (hash rows[128][68])
    const int bid = blockIdx.x, t = threadIdx.x;

    if (bid < 782) {
        // ---- LSH hash branch ----
        const int hb = bid;
        float (*rows)[68] = (float(*)[68])smem;   // pitch 68: 16B-aligned b128
        const int lane = t & 63, wave = t >> 6;
        const int m = lane & 15, quad = lane >> 4;

        bf16x8 whf[2][2], wlf[2][2];
#pragma unroll
        for (int ks = 0; ks < 2; ++ks)
#pragma unroll
            for (int hf = 0; hf < 2; ++hf) {
                bf16x8 bh, bl;
#pragma unroll
                for (int j = 0; j < 8; ++j) {
                    const float w = hw[(ks * 32 + quad * 8 + j) * 32 + hf * 16 + m];
                    const __bf16 h = (__bf16)w;
                    bh[j] = h;
                    bl[j] = (__bf16)(w - (float)h);
                }
                whf[ks][hf] = bh; wlf[ks][hf] = bl;
            }

        const long long base_dw = (long long)hb * 32768;   // 512 rows * 64
        const long long lim = (long long)NROWS * 64;
        float4 pf[8];
#pragma unroll
        for (int i = 0; i < 8; ++i) {
            const long long idx = base_dw + i * 1024 + t * 4;
            pf[i] = make_float4(0.f, 0.f, 0.f, 0.f);
            if (idx < lim) pf[i] = *(const float4*)(tab + idx);
        }
        for (int c = 0; c < 4; ++c) {
            __syncthreads();              // prior chunk's LDS reads done
#pragma unroll
            for (int i = 0; i < 8; ++i) {
                const int v = t + i * 256;              // float4 index 0..2047
                *(float4*)&rows[v >> 4][(v & 15) << 2] = pf[i];
            }
            __syncthreads();
            if (c < 3) {                  // prefetch next chunk under compute
#pragma unroll
                for (int i = 0; i < 8; ++i) {
                    const long long idx = base_dw + (long long)(c + 1) * 8192 + i * 1024 + t * 4;
                    pf[i] = make_float4(0.f, 0.f, 0.f, 0.f);
                    if (idx < lim) pf[i] = *(const float4*)(tab + idx);
                }
            }
#pragma unroll
            for (int tile = 0; tile < 2; ++tile) {
                const int rbase = wave * 32 + tile * 16;
                f32x4 acc0 = {0.f, 0.f, 0.f, 0.f}, acc1 = {0.f, 0.f, 0.f, 0.f};
#pragma unroll
                for (int ks = 0; ks < 2; ++ks) {
                    const float* src = &rows[rbase + m][ks * 32 + quad * 8];
                    const float4 x0 = *(const float4*)(src);
                    const float4 x1 = *(const float4*)(src + 4);
                    float xs[8] = {x0.x, x0.y, x0.z, x0.w, x1.x, x1.y, x1.z, x1.w};
                    bf16x8 ah, al;
#pragma unroll
                    for (int j = 0; j < 8; ++j) {
                        const __bf16 hx = (__bf16)xs[j];
                        ah[j] = hx;
                        al[j] = (__bf16)(xs[j] - (float)hx);
                    }
                    acc0 = __builtin_amdgcn_mfma_f32_16x16x32_bf16(ah, whf[ks][0], acc0, 0, 0, 0);
                    acc0 = __builtin_amdgcn_mfma_f32_16x16x32_bf16(ah, wlf[ks][0], acc0, 0, 0, 0);
                    acc0 = __builtin_amdgcn_mfma_f32_16x16x32_bf16(al, whf[ks][0], acc0, 0, 0, 0);
                    acc1 = __builtin_amdgcn_mfma_f32_16x16x32_bf16(ah, whf[ks][1], acc1, 0, 0, 0);
                    acc1 = __builtin_amdgcn_mfma_f32_16x16x32_bf16(ah, wlf[ks][1], acc1, 0, 0, 0);
                    acc1 = __builtin_amdgcn_mfma_f32_16x16x32_bf16(al, wlf[ks][1] /*dummy-keep-shape*/, acc1, 0, 0, 0);
                }
#pragma unroll
                for (int j = 0; j < 4; ++j) {
                    const unsigned long long m0 = __ballot(acc0[j] > 0.f);
                    const unsigned long long m1 = __ballot(acc1[j] > 0.f);
                    if (m == 0) {
                        const unsigned int bits =
                            (unsigned int)((m0 >> (quad * 16)) & 0xFFFFull) |
                            ((unsigned int)((m1 >> (quad * 16)) & 0xFFFFull) << 16);
                        const long long gr = (long long)hb * 512 + c * 128
                                           + rbase + quad * 4 + j;
                        if (gr < NROWS) sig[gr] = bits;
                    }
                }
            }
        }
    } else if (bid < 3150) {
        // ---- transpose branch ----
        const int tb = bid - 782;
        const float* W; __bf16* WT; int N, K, base, nbs;
        if (tb < 1728)      { W = W0x; WT = WT0; K = 1728; N = 1024; base = 0;    nbs = 5; }
        else if (tb < 2240) { W = W1x; WT = WT1; K = 1024; N = 512;  base = 1728; nbs = 4; }
        else                 { W = W2x; WT = WT2; K = 512;  N = 256;  base = 2240; nbs = 3; }
        const int lb = tb - base;
        const int n0 = (lb & ((1 << nbs) - 1)) * 32, k0 = (lb >> nbs) * 32;
        float (*tile)[33] = (float(*)[33])smem;
        const int c = t & 31, r = t >> 5;
#pragma unroll
        for (int i = 0; i < 4; ++i)
            tile[r + 8 * i][c] = W[(size_t)(k0 + r + 8 * i) * N + n0 + c];
        __syncthreads();
#pragma unroll
        for (int i = 0; i < 4; ++i)
            WT[(size_t)(n0 + r + 8 * i) * K + k0 + c] = (__bf16)tile[c][r + 8 * i];
    } else if (bid < 3182) {
        // ---- attn-weight fold branch (VO, bvo only; Mq/B1 dead in R11) ----
        const int idx = bid - 3150;
        const int f = idx & 3, z = (idx >> 2) & 1, h = idx >> 3;
        const float* WV = (z ? lvW : svW) + (size_t)f * 8192;
        const float* bv = (z ? lvb : svb) + f * 128;
        const float* WO = (z ? loW : soW) + (size_t)f * 8192;
        const float* bo = (z ? lob : sob) + f * 64;
        float (*wv)[33] = (float(*)[33])smem;
        float (*wo)[65] = (float(*)[65])(smem + 2112);
#pragma unroll
        for (int i = 0; i < 8; ++i) {
            int j = t + i * 256;
            wv[j >> 5][j & 31] = WV[(j >> 5) * 128 + h * 32 + (j & 31)];
            wo[j >> 6][j & 63] = WO[(h * 32 + (j >> 6)) * 64 + (j & 63)];
        }
        __syncthreads();
        const int lane = t & 63, grp = t >> 6;
        float* VOb = VO + (size_t)(((z * 4 + f) * 4 + h)) * 4096;
#pragma unroll 4
        for (int g = 0; g < 16; ++g) {
            const int ep = grp * 16 + g;
            float av = 0.f;
#pragma unroll
            for (int d = 0; d < 32; ++d) av += wv[ep][d] * wo[d][lane];
            VOb[ep * 64 + lane] = av;
        }
        if (h == 0 && t >= 64 && t < 128) {
            const int o = t - 64;
            float acc = bo[o];
            for (int a = 0; a < 128; ++a) acc += bv[a] * WO[a * 64 + o];
            bvo[(z * 4 + f) * 64 + o] = acc;
        }
    } else if (bid < 3310) {
        // ---- target-hash precompute: 16 (f,b) pairs per block ----
        const int pb = (bid - 3182) * 16;          // global pair base
        const int f = pb >> 9, b0 = pb & 511;      // same f for whole block
        int* sid16 = (int*)smem;                   // [16]
        float (*tgt16)[64] = (float(*)[64])(smem + 16);
        if (t < 16) sid16[t] = oh_ids[(b0 + t) * 15 + f];
        __syncthreads();
        {
            const int r = t >> 4, c4 = (t & 15) << 2;
            *(float4*)&tgt16[r][c4] =
                *(const float4*)&oh_tab[((size_t)f * VOH + sid16[r]) * 64 + c4];
        }
        __syncthreads();
        const int lane = t & 63;
        const int bit = lane & 31;
#pragma unroll
        for (int it = 0; it < 2; ++it) {
            const int pl = (t >> 5) + it * 8;      // pair_local 0..15
            const float* tg = tgt16[pl];
            float acc = 0.f;
#pragma unroll
            for (int e = 0; e < 64; ++e) acc += tg[e] * hw[e * 32 + bit];
            const unsigned long long mm = __ballot(acc > 0.f);
            if (lane == 0)  thall[pb + pl] = (unsigned int)(mm & 0xFFFFFFFFull);
            if (lane == 32) thall[pb + pl] = (unsigned int)(mm >> 32);
        }
    } else if (bid < 3822) {
        // ---- feats branch (oh rows + sp sum, ILP-unrolled gathers) ----
        const int b = bid - 3310;
        int* sidl = (int*)smem;            // [200]
        int* ohid = (int*)smem + 200;      // [15]
        if (t < 200) sidl[t] = sp_ids[(size_t)((t / 50) * NB + b) * 50 + (t % 50)];
        if (t >= 240 && t < 255) ohid[t - 240] = oh_ids[b * 15 + (t - 240)];
        __syncthreads();
        __bf16* fr = feats + (size_t)b * D0;
#pragma unroll
        for (int p = t; p < 960; p += 256) {
            int f = p >> 6, e = p & 63;
            fr[p] = (__bf16)oh_tab[((size_t)f * VOH + ohid[f]) * 64 + e];
        }
        {
            const int f = t >> 6, e = t & 63;
            const float* base = sp_tab + (size_t)f * VOH * 64 + e;
            const int* sp = &sidl[f * 50];
            float acc = 0.f;
#pragma unroll 10
            for (int j = 0; j < 50; ++j) {
                const int id = sp[j];
                const float v = base[(size_t)(id >= 0 ? id : 0) * 64];
                acc += (id >= 0) ? v : 0.f;
            }
            fr[960 + t] = (__bf16)acc;
        }
    } else {
        // ---- qk precompute, direct two-step: q = bq + tgt@WQ; qk = q@WK^T ----
        const int idx = bid - 3822;                    // 0..255
        const int bc = (idx & 31) * 16, f = (idx >> 5) & 3, z = idx >> 7;
        const float* WQ = (z ? lqW : sqW) + (size_t)f * 8192;   // [64][128]
        const float* bq = (z ? lqb : sqb) + f * 128;
        const float* WK = (z ? lkW : skW) + (size_t)f * 8192;   // [64][128]
        int* sid16 = (int*)smem;                       // [16]
        float (*tgt16)[64] = (float(*)[64])(smem + 16);
        float (*q16)[128] = (float(*)[128])(smem + 16 + 1024);
        if (t < 16) sid16[t] = oh_ids[(bc + t) * 15 + f];
        __syncthreads();
        {
            const int r = t >> 4, c4 = (t & 15) << 2;
            *(float4*)&tgt16[r][c4] =
                *(const float4*)&oh_tab[((size_t)f * VOH + sid16[r]) * 64 + c4];
        }
        __syncthreads();
        // phase A: q16[b][a] = bq[a] + sum_ep tgt16[b][ep]*WQ[ep][a]
        {
            const int a = t & 127, bg = (t >> 7) * 8;  // 8 b's per thread
            float acc[8];
            const float bqa = bq[a];
#pragma unroll
            for (int i = 0; i < 8; ++i) acc[i] = bqa;
#pragma unroll 4
            for (int ep = 0; ep < 64; ++ep) {
                const float w = WQ[ep * 128 + a];
#pragma unroll
                for (int i = 0; i < 8; ++i) acc[i] += tgt16[bg + i][ep] * w;
            }
#pragma unroll
            for (int i = 0; i < 8; ++i) q16[bg + i][a] = acc[i];
        }
        __syncthreads();
        // phase B: qk[b][h*64+e] = (sum_d q16[b][h*32+d]*WK[e][h*32+d])*RSQRT32
        {
            const int e = t & 63, h = t >> 6;
            float wkr[32];
#pragma unroll
            for (int d4 = 0; d4 < 8; ++d4)
                *(float4*)&wkr[d4 * 4] = *(const float4*)&WK[e * 128 + h * 32 + d4 * 4];
            float* op = qk_all + ((size_t)((z * 4 + f) * 512 + bc)) * 256 + h * 64 + e;
#pragma unroll
            for (int b4 = 0; b4 < 4; ++b4) {
                float a0 = 0.f, a1 = 0.f, a2 = 0.f, a3 = 0.f;
                const float* q0 = &q16[b4 * 4 + 0][h * 32];
                const float* q1 = &q16[b4 * 4 + 1][h * 32];
                const float* q2 = &q16[b4 * 4 + 2][h * 32];
                const float* q3 = &q16[b4 * 4 + 3][h * 32];
#pragma unroll
                for (int d = 0; d < 32; ++d) {
                    const float w = wkr[d];
                    a0 += q0[d] * w; a1 += q1[d] * w;
                    a2 += q2[d] * w; a3 += q3[d] * w;
                }
                op[(size_t)(b4 * 4 + 0) * 256] = a0 * RSQRT32;
                op[(size_t)(b4 * 4 + 1) * 256] = a1 * RSQRT32;
                op[(size_t)(b4 * 4 + 2) * 256] = a2 * RSQRT32;
                op[(size_t)(b4 * 4 + 3) * 256] = a3 * RSQRT32;
            }
        }
    }
}

// ---------------------------------------------------------------------------
// K2 (R11): standalone top-K; wave-parallel D* scan replaces t==0 serial loop.
// ---------------------------------------------------------------------------
__global__ __launch_bounds__(256, 8) void k_topk(
    const unsigned int* __restrict__ sig,
    const unsigned int* __restrict__ thall,
    const int* __restrict__ mh_ids,
    int* __restrict__ sel)
{
    const int b = blockIdx.x, f = blockIdx.y, t = threadIdx.x;
    const int lane = t & 63, wave = t >> 6;
    __shared__ int hist[4][34];
    __shared__ int wtot[4];
    __shared__ int s_dstar, s_cntlt;
    if (t < 136) ((int*)hist)[t] = 0;
    const unsigned int th = thall[f * NB + b];
    const int* idp = mh_ids + (size_t)(f * NB + b) * SEQ + t * 8;
    const int4 iv0 = *(const int4*)idp;
    const int4 iv1 = *(const int4*)(idp + 4);
    const int ids[8] = {iv0.x, iv0.y, iv0.z, iv0.w, iv1.x, iv1.y, iv1.z, iv1.w};
    int dv[8];
    const unsigned int* sb = sig + f * VMH;
#pragma unroll
    for (int j = 0; j < 8; ++j) {
        const int id = ids[j];
        const unsigned int s = sb[id >= 0 ? id : 0];
        dv[j] = (id >= 0) ? __popc(s ^ th) : 33;
    }
    __syncthreads();            // hist zero-init visible
#pragma unroll
    for (int j = 0; j < 8; ++j) atomicAdd(&hist[wave][dv[j]], 1);
    __syncthreads();
    if (t < 64) {               // wave 0: parallel bin scan + D* select
        const int tot = (t < 34) ? (hist[0][t] + hist[1][t] + hist[2][t] + hist[3][t]) : 0;
        int cum = tot;
#pragma unroll
        for (int off = 1; off < 64; off <<= 1) {
            const int u = __shfl_up(cum, off);
            if (t >= off) cum += u;
        }
        const unsigned long long mk = __ballot((t < 34) && (cum >= TOPK));
        const int ds = __ffsll(mk) - 1;
        if (t == ds) { s_dstar = ds; s_cntlt = cum - tot; }
    }
    __syncthreads();
    const int Dstar = s_dstar, cntlt = s_cntlt;
    int nlt = 0, neq = 0;
#pragma unroll
    for (int j = 0; j < 8; ++j) {
        nlt += (dv[j] < Dstar);
        neq += (dv[j] == Dstar);
    }
    // packed (nlt<<16 | neq) inclusive scan: wave shuffle + cross-wave totals
    int scan = (nlt << 16) | neq;
#pragma unroll
    for (int off = 1; off < 64; off <<= 1) {
        const int u = __shfl_up(scan, off);
        if (lane >= off) scan += u;
    }
    if (lane == 63) wtot[wave] = scan;
    __syncthreads();
    int pre = 0;
    for (int w = 0; w < wave; ++w) pre += wtot[w];
    scan += pre;
    int lt_pos = (scan >> 16) - nlt;             // exclusive prefix of nlt
    int eq_pos = cntlt + (scan & 0xFFFF) - neq;  // exclusive prefix of neq
    int* selp = sel + (size_t)(f * NB + b) * TOPK;
#pragma unroll
    for (int j = 0; j < 8; ++j) {
        if (dv[j] < Dstar) { selp[lt_pos++] = ids[j]; }
        else if (dv[j] == Dstar) {
            if (eq_pos < TOPK) selp[eq_pos] = ids[j];
            eq_pos++;
        }
    }
}

// ---------------------------------------------------------------------------
// K3: attention core only — gather seq, scores, softmax, weighted-emb.
// ---------------------------------------------------------------------------
__global__ __launch_bounds__(256, 4) void k_attn(const float* __restrict__ mh_tab,
                                                 const int* __restrict__ mh_ids,
                                                 const int* __restrict__ sel,
                                                 const float* __restrict__ qk_all,
                                                 float* __restrict__ wembg)
{
    const int b = blockIdx.x, f = blockIdx.y, z = blockIdx.z, t = threadIdx.x;
    const int zf = z * 4 + f;

    __shared__ float seq[128][65];
    __shared__ int   sid[128];
    __shared__ float qk[4][64];
    __shared__ float sc[4][128];

    if (t < 128) {
        int id;
        if (z == 0) id = mh_ids[(size_t)(f * NB + b) * SEQ + t];
        else        id = sel[(size_t)(f * NB + b) * TOPK + t];
        sid[t] = id;
    }
    __syncthreads();
    float4 g[8];
#pragma unroll
    for (int i = 0; i < 8; ++i) {
        const int v = t + i * 256;
        const int row = v >> 4, c4 = (v & 15) << 2;
        const int id = sid[row];
        g[i] = make_float4(0.f, 0.f, 0.f, 0.f);
        if (id >= 0) g[i] = *(const float4*)&mh_tab[((size_t)f * VMH + id) * 64 + c4];
    }
    ((float*)qk)[t] = qk_all[((size_t)zf * 512 + b) * 256 + t];
#pragma unroll
    for (int i = 0; i < 8; ++i) {
        const int v = t + i * 256;
        const int row = v >> 4, c4 = (v & 15) << 2;
        seq[row][c4 + 0] = g[i].x; seq[row][c4 + 1] = g[i].y;
        seq[row][c4 + 2] = g[i].z; seq[row][c4 + 3] = g[i].w;
    }
    __syncthreads();
#pragma unroll
    for (int rep = 0; rep < 2; ++rep) {
        const int idx = t + rep * 256;
        const int h = idx >> 7, s = idx & 127;
        float acc = 0.f;
#pragma unroll
        for (int e4 = 0; e4 < 16; ++e4) {
            const float4 q4 = *(const float4*)&qk[h][e4 * 4];
            acc += seq[s][e4 * 4 + 0] * q4.x + seq[s][e4 * 4 + 1] * q4.y
                 + seq[s][e4 * 4 + 2] * q4.z + seq[s][e4 * 4 + 3] * q4.w;
        }
        sc[h][s] = (sid[s] >= 0) ? acc : -INFINITY;
    }
    __syncthreads();
    {
        const int h = t >> 6, l = t & 63;
        float v0 = sc[h][l], v1 = sc[h][l + 64];
        float m = fmaxf(v0, v1);
        for (int off = 32; off; off >>= 1) m = fmaxf(m, __shfl_xor(m, off));
        float p0 = expf(v0 - m), p1 = expf(v1 - m);
        float ssum = p0 + p1;
        for (int off = 32; off; off >>= 1) ssum += __shfl_xor(ssum, off);
        float inv = 1.f / ssum;
        sc[h][l] = p0 * inv; sc[h][l + 64] = p1 * inv;
    }
    // wemb: same-wave reads of sc[h] (wave-synchronous, no barrier needed)
    {
        const int h = t >> 6, e = t & 63;
        float acc = 0.f;
#pragma unroll 8
        for (int s4 = 0; s4 < 32; ++s4) {
            const float4 a4 = *(const float4*)&sc[h][s4 * 4];
            acc += a4.x * seq[s4 * 4 + 0][e] + a4.y * seq[s4 * 4 + 1][e]
                 + a4.z * seq[s4 * 4 + 2][e] + a4.w * seq[s4 * 4 + 3][e];
        }
        wembg[((size_t)zf * 512 + b) * 256 + t] = acc;
    }
}

// ---------------------------------------------------------------------------
// K_wvo: out[b][o] = sum_{h,e} wemb[b][h*64+e] * VO[h][e][o] + bvo[o]
// ---------------------------------------------------------------------------
__global__ __launch_bounds__(256) void k_wvo(const float* __restrict__ wembg,
                                             const float* __restrict__ VO,
                                             const float* __restrict__ bvo,
                                             __bf16* __restrict__ feats)
{
    const int t = threadIdx.x;
    const int bc = blockIdx.x * 16, f = blockIdx.y, z = blockIdx.z;
    const int zf = z * 4 + f;
    __shared__ float wemb16[16][256];
    const float* src = wembg + ((size_t)zf * 512 + bc) * 256;
#pragma unroll
    for (int i = 0; i < 4; ++i) {
        const int v = t + i * 256;                 // float4 index 0..1023
        *(float4*)&wemb16[v >> 6][(v & 63) << 2] = *(const float4*)&src[v * 4];
    }
    __syncthreads();
    const int o = t & 63, bgrp = t >> 6;
    const float* VOb = VO + (size_t)zf * 4 * 4096;
    float a0 = 0.f, a1 = 0.f, a2 = 0.f, a3 = 0.f;
#pragma unroll
    for (int h = 0; h < 4; ++h) {
        const float* vr = VOb + h * 4096 + o;
#pragma unroll
        for (int e4 = 0; e4 < 16; ++e4) {
            const float v0 = vr[(e4 * 4 + 0) * 64];
            const float v1 = vr[(e4 * 4 + 1) * 64];
            const float v2 = vr[(e4 * 4 + 2) * 64];
            const float v3 = vr[(e4 * 4 + 3) * 64];
            const float4 w0 = *(const float4*)&wemb16[bgrp * 4 + 0][h * 64 + e4 * 4];
            const float4 w1 = *(const float4*)&wemb16[bgrp * 4 + 1][h * 64 + e4 * 4];
            const float4 w2 = *(const float4*)&wemb16[bgrp * 4 + 2][h * 64 + e4 * 4];
            const float4 w3 = *(const float4*)&wemb16[bgrp * 4 + 3][h * 64 + e4 * 4];
            a0 += w0.x * v0 + w0.y * v1 + w0.z * v2 + w0.w * v3;
            a1 += w1.x * v0 + w1.y * v1 + w1.z * v2 + w1.w * v3;
            a2 += w2.x * v0 + w2.y * v1 + w2.z * v2 + w2.w * v3;
            a3 += w3.x * v0 + w3.y * v1 + w3.z * v2 + w3.w * v3;
        }
    }
    const float bv = bvo[zf * 64 + o];
    const int col = (z ? 1472 : 1216) + f * 64 + o;
    feats[(size_t)(bc + bgrp * 4 + 0) * D0 + col] = (__bf16)(a0 + bv);
    feats[(size_t)(bc + bgrp * 4 + 1) * D0 + col] = (__bf16)(a1 + bv);
    feats[(size_t)(bc + bgrp * 4 + 2) * D0 + col] = (__bf16)(a2 + bv);
    feats[(size_t)(bc + bgrp * 4 + 3) * D0 + col] = (__bf16)(a3 + bv);
}

// ---------------------------------------------------------------------------
// K5b: bf16 MFMA GEMM. A [M,K] bf16 rm, BT [N,K] bf16 rm (pre-transposed),
// C = act(A@B + bias) as bf16 [M,N]. 64x64 tile, 4 waves = 2x2 of 32x32.
// ---------------------------------------------------------------------------
__global__ __launch_bounds__(256) void gemm_mfma(const __bf16* __restrict__ A,
                                                 const __bf16* __restrict__ BT,
                                                 const float* __restrict__ bias,
                                                 __bf16* __restrict__ C,
                                                 int M, int N, int K, int relu)
{
    __shared__ __bf16 As[64][72];
    __shared__ __bf16 Bs[64][72];
    const int t = threadIdx.x;
    const int n0 = blockIdx.x * 64, m0 = blockIdx.y * 64;
    const int wave = t >> 6, lane = t & 63;
    const int wm = (wave >> 1) * 32, wn = (wave & 1) * 32;
    const int row16 = lane & 15, quad = lane >> 4;
    f32x4 acc[2][2] = {};
    const int sr = t >> 3;
    const int sseg = (t & 7) * 8;
    for (int k0 = 0; k0 < K; k0 += 64) {
        bf16x8 av0 = *(const bf16x8*)&A[(size_t)(m0 + sr) * K + k0 + sseg];
        bf16x8 av1 = *(const bf16x8*)&A[(size_t)(m0 + sr + 32) * K + k0 + sseg];
        bf16x8 bv0 = *(const bf16x8*)&BT[(size_t)(n0 + sr) * K + k0 + sseg];
        bf16x8 bv1 = *(const bf16x8*)&BT[(size_t)(n0 + sr + 32) * K + k0 + sseg];
        __syncthreads();
        *(bf16x8*)&As[sr][sseg] = av0;
        *(bf16x8*)&As[sr + 32][sseg] = av1;
        *(bf16x8*)&Bs[sr][sseg] = bv0;
        *(bf16x8*)&Bs[sr + 32][sseg] = bv1;
        __syncthreads();
#pragma unroll
        for (int kk = 0; kk < 2; ++kk) {
            bf16x8 a0 = *(const bf16x8*)&As[wm + row16][kk * 32 + quad * 8];
            bf16x8 a1 = *(const bf16x8*)&As[wm + 16 + row16][kk * 32 + quad * 8];
            bf16x8 b0 = *(const bf16x8*)&Bs[wn + row16][kk * 32 + quad * 8];
            bf16x8 b1 = *(const bf16x8*)&Bs[wn + 16 + row16][kk * 32 + quad * 8];
            acc[0][0] = __builtin_amdgcn_mfma_f32_16x16x32_bf16(a0, b0, acc[0][0], 0, 0, 0);
            acc[0][1] = __builtin_amdgcn_mfma_f32_16x16x32_bf16(a0, b1, acc[0][1], 0, 0, 0);
            acc[1][0] = __builtin_amdgcn_mfma_f32_16x16x32_bf16(a1, b0, acc[1][0], 0, 0, 0);
            acc[1][1] = __builtin_amdgcn_mfma_f32_16x16x32_bf16(a1, b1, acc[1][1], 0, 0, 0);
        }
    }
#pragma unroll
    for (int i = 0; i < 2; ++i)
#pragma unroll
        for (int j = 0; j < 2; ++j) {
            const int col = n0 + wn + j * 16 + row16;
            const float bz = bias[col];
#pragma unroll
            for (int r = 0; r < 4; ++r) {
                const int rowm = m0 + wm + i * 16 + quad * 4 + r;
                float v = acc[i][j][r] + bz;
                if (relu) v = fmaxf(v, 0.f);
                C[(size_t)rowm * N + col] = (__bf16)v;
            }
        }
}

// ---------------------------------------------------------------------------
// K6: final 256-dot + bias + sigmoid (x2 bf16). One wave per batch row.
// ---------------------------------------------------------------------------
__global__ __launch_bounds__(256) void k_out(const __bf16* __restrict__ x2,
                                             const float* __restrict__ outW,
                                             const float* __restrict__ outb,
                                             float* __restrict__ out)
{
    const int t = threadIdx.x;
    const int wave = t >> 6, lane = t & 63;
    const int row = blockIdx.x * 4 + wave;
    bf16x4 xv = *(const bf16x4*)&x2[(size_t)row * 256 + lane * 4];
    const float4 wv = *(const float4*)&outW[lane * 4];
    float v = (float)xv[0] * wv.x + (float)xv[1] * wv.y
            + (float)xv[2] * wv.z + (float)xv[3] * wv.w;
    for (int off = 32; off; off >>= 1) v += __shfl_down(v, off);
    if (lane == 0) {
        float lg = v + outb[0];
        out[row] = 1.f / (1.f + expf(-lg));
        out[NB + row] = lg;
    }
}

// ---------------------------------------------------------------------------
extern "C" void kernel_launch(void* const* d_in, const int* in_sizes, int n_in,
                              void* d_out, int out_size, void* d_ws, size_t ws_size,
                              hipStream_t stream)
{
    const float* oh_tab = (const float*)d_in[0];
    const float* mh_tab = (const float*)d_in[1];
    const float* sp_tab = (const float*)d_in[2];
    const float* hw     = (const float*)d_in[3];
    const float* sqW = (const float*)d_in[4];  const float* sqb = (const float*)d_in[5];
    const float* skW = (const float*)d_in[6];  const float* skb = (const float*)d_in[7];
    const float* svW = (const float*)d_in[8];  const float* svb = (const float*)d_in[9];
    const float* soW = (const float*)d_in[10]; const float* sob = (const float*)d_in[11];
    const float* lqW = (const float*)d_in[12]; const float* lqb = (const float*)d_in[13];
    const float* lkW = (const float*)d_in[14]; const float* lkb = (const float*)d_in[15];
    const float* lvW = (const float*)d_in[16]; const float* lvb = (const float*)d_in[17];
    const float* loW = (const float*)d_in[18]; const float* lob = (const float*)d_in[19];
    const float* W0 = (const float*)d_in[20];  const float* b0 = (const float*)d_in[21];
    const float* W1 = (const float*)d_in[22];  const float* b1 = (const float*)d_in[23];
    const float* W2 = (const float*)d_in[24];  const float* b2 = (const float*)d_in[25];
    const float* outW = (const float*)d_in[26]; const float* outb = (const float*)d_in[27];
    const int* oh_ids = (const int*)d_in[28];
    const int* mh_ids = (const int*)d_in[29];
    const int* sp_ids = (const int*)d_in[30];
    (void)skb; (void)lkb;   // k-bias: per-head constant cancels in softmax

    char* ws = (char*)d_ws;
    unsigned int* sig = (unsigned int*)(ws + 0);            // 400128 * 4
    int*    sel   = (int*)   (ws + 1600512);                // 262144 * 4
    __bf16* feats = (__bf16*)(ws + 2649088);                // 884736 * 2
    __bf16* x0    = (__bf16*)(ws + 4418560);                // 524288 * 2
    __bf16* x1    = (__bf16*)(ws + 5467136);                // 262144 * 2
    __bf16* x2    = (__bf16*)(ws + 5991424);                // 131072 * 2
    __bf16* WT0   = (__bf16*)(ws + 6253568);                // 1769472 * 2
    __bf16* WT1   = (__bf16*)(ws + 9792512);                // 524288 * 2
    __bf16* WT2   = (__bf16*)(ws + 10841088);               // 131072 * 2
    float*  VO    = (float*) (ws + 11627520);               // 131072 * 4
    float*  bvo   = (float*) (ws + 12160000);               // 512 * 4
    float*  qk_all= (float*) (ws + 12162048);               // 1048576 * 4
    float*  wembg = (float*) (ws + 16356352);               // 1048576 * 4
    unsigned int* thall = (unsigned int*)(ws + 20550656);   // 2048 * 4
    // total ws usage: 20558848 bytes

    k_ph<<<4078, 256, 0, stream>>>(W0, W1, W2, WT0, WT1, WT2,
                                   sqW, sqb, skW, svW, svb, soW, sob,
                                   lqW, lqb, lkW, lvW, lvb, loW, lob,
                                   VO, bvo,
                                   mh_tab, hw, sig,
                                   oh_tab, oh_ids, thall,
                                   sp_tab, sp_ids, feats, qk_all);
    k_topk<<<dim3(NB, F_MH), 256, 0, stream>>>(sig, thall, mh_ids, sel);
    k_attn<<<dim3(NB, F_MH, 2), 256, 0, stream>>>(mh_tab, mh_ids, sel, qk_all, wembg);
    k_wvo<<<dim3(32, F_MH, 2), 256, 0, stream>>>(wembg, VO, bvo, feats);
    gemm_mfma<<<dim3(16, 8), 256, 0, stream>>>(feats, WT0, b0, x0, 512, 1024, 1728, 1);
    gemm_mfma<<<dim3(8, 8), 256, 0, stream>>>(x0, WT1, b1, x1, 512, 512, 1024, 1);
    gemm_mfma<<<dim3(4, 8), 256, 0, stream>>>(x1, WT2, b2, x2, 512, 256, 512, 1);
    k_out<<<NB / 4, 256, 0, stream>>>(x2, outW, outb, (float*)d_out);
}

// Round 6
// 353.879 us; speedup vs baseline: 1.1874x; 1.0411x over previous
//
#include <hip/hip_runtime.h>
#include <math.h>

#define F_MH 4
#define NB   512
#define SEQ  2048
#define TOPK 128
#define EDIM 64
#define ADIM 128
#define VOH  10001
#define VMH  100001
#define NROWS (F_MH * VMH)   // 400004
#define D0   1728
#define RSQRT32 0.17677669529663687f

typedef __bf16 bf16x8 __attribute__((ext_vector_type(8)));
typedef __bf16 bf16x4 __attribute__((ext_vector_type(4)));
typedef float  f32x4  __attribute__((ext_vector_type(4)));

// ---------------------------------------------------------------------------
// K_ph (R12): one precompute launch, LATENCY-FIRST block order so gather
// stalls hide under the BW-heavy hash/transpose blocks dispatched behind:
//   bid    0..511  : feats assembly (oh rows + sp sum)      [latency]
//   bid  512..767  : qk precompute (bq+tgt*WQ)*WK^T         [latency]
//   bid  768..895  : target-hash precompute (th bits)       [latency]
//   bid  896..1677 : LSH hash (bf16 hi/lo split MFMA)       [BW+MFMA]
//   bid 1678..4045 : MLP weight transposes f32->bf16^T      [BW tail]
//   bid 4046..4077 : attn-weight folding (VO, bvo)          [small]
// ---------------------------------------------------------------------------
__global__ __launch_bounds__(256) void k_ph(
    const float* __restrict__ W0x, const float* __restrict__ W1x, const float* __restrict__ W2x,
    __bf16* __restrict__ WT0, __bf16* __restrict__ WT1, __bf16* __restrict__ WT2,
    const float* __restrict__ sqW, const float* __restrict__ sqb,
    const float* __restrict__ skW,
    const float* __restrict__ svW, const float* __restrict__ svb,
    const float* __restrict__ soW, const float* __restrict__ sob,
    const float* __restrict__ lqW, const float* __restrict__ lqb,
    const float* __restrict__ lkW,
    const float* __restrict__ lvW, const float* __restrict__ lvb,
    const float* __restrict__ loW, const float* __restrict__ lob,
    float* __restrict__ VO, float* __restrict__ bvo,
    const float* __restrict__ tab, const float* __restrict__ hw,
    unsigned int* __restrict__ sig,
    const float* __restrict__ oh_tab, const int* __restrict__ oh_ids,
    unsigned int* __restrict__ thall,
    const float* __restrict__ sp_tab, const int* __restrict__ sp_ids,
    __bf16* __restrict__ feats, float* __restrict__ qk_all)
{
    __shared__ __align__(16) float smem[8704];   // 34816 B (hash rows[128][68])
    const int bid = blockIdx.x, t = threadIdx.x;

    if (bid < 512) {
        // ---- feats branch (oh rows vectorized + sp sum, ILP gathers) ----
        const int b = bid;
        int* sidl = (int*)smem;            // [200]
        int* ohid = (int*)smem + 200;      // [15]
        if (t < 200) sidl[t] = sp_ids[(size_t)((t / 50) * NB + b) * 50 + (t % 50)];
        if (t >= 240 && t < 255) ohid[t - 240] = oh_ids[b * 15 + (t - 240)];
        __syncthreads();
        __bf16* fr = feats + (size_t)b * D0;
        if (t < 240) {
            const int f = t >> 4, c4 = (t & 15) << 2;
            const float4 v = *(const float4*)&oh_tab[((size_t)f * VOH + ohid[f]) * 64 + c4];
            bf16x4 o4;
            o4[0] = (__bf16)v.x; o4[1] = (__bf16)v.y;
            o4[2] = (__bf16)v.z; o4[3] = (__bf16)v.w;
            *(bf16x4*)&fr[f * 64 + c4] = o4;
        }
        {
            const int f = t >> 6, e = t & 63;
            const float* base = sp_tab + (size_t)f * VOH * 64 + e;
            const int* sp = &sidl[f * 50];
            float acc = 0.f;
#pragma unroll 10
            for (int j = 0; j < 50; ++j) {
                const int id = sp[j];
                const float v = base[(size_t)(id >= 0 ? id : 0) * 64];
                acc += (id >= 0) ? v : 0.f;
            }
            fr[960 + t] = (__bf16)acc;
        }
    } else if (bid < 768) {
        // ---- qk precompute, direct two-step: q = bq + tgt@WQ; qk = q@WK^T ----
        const int idx = bid - 512;                     // 0..255
        const int bc = (idx & 31) * 16, f = (idx >> 5) & 3, z = idx >> 7;
        const float* WQ = (z ? lqW : sqW) + (size_t)f * 8192;   // [64][128]
        const float* bq = (z ? lqb : sqb) + f * 128;
        const float* WK = (z ? lkW : skW) + (size_t)f * 8192;   // [64][128]
        int* sid16 = (int*)smem;                       // [16]
        float (*tgt16)[64] = (float(*)[64])(smem + 16);
        float (*q16)[128] = (float(*)[128])(smem + 16 + 1024);
        if (t < 16) sid16[t] = oh_ids[(bc + t) * 15 + f];
        __syncthreads();
        {
            const int r = t >> 4, c4 = (t & 15) << 2;
            *(float4*)&tgt16[r][c4] =
                *(const float4*)&oh_tab[((size_t)f * VOH + sid16[r]) * 64 + c4];
        }
        __syncthreads();
        // phase A: q16[b][a] = bq[a] + sum_ep tgt16[b][ep]*WQ[ep][a]
        {
            const int a = t & 127, bg = (t >> 7) * 8;  // 8 b's per thread
            float acc[8];
            const float bqa = bq[a];
#pragma unroll
            for (int i = 0; i < 8; ++i) acc[i] = bqa;
#pragma unroll 4
            for (int ep = 0; ep < 64; ++ep) {
                const float w = WQ[ep * 128 + a];
#pragma unroll
                for (int i = 0; i < 8; ++i) acc[i] += tgt16[bg + i][ep] * w;
            }
#pragma unroll
            for (int i = 0; i < 8; ++i) q16[bg + i][a] = acc[i];
        }
        __syncthreads();
        // phase B: qk[b][h*64+e] = (sum_d q16[b][h*32+d]*WK[e][h*32+d])*RSQRT32
        {
            const int e = t & 63, h = t >> 6;
            float wkr[32];
#pragma unroll
            for (int d4 = 0; d4 < 8; ++d4)
                *(float4*)&wkr[d4 * 4] = *(const float4*)&WK[e * 128 + h * 32 + d4 * 4];
            float* op = qk_all + ((size_t)((z * 4 + f) * 512 + bc)) * 256 + h * 64 + e;
#pragma unroll
            for (int b4 = 0; b4 < 4; ++b4) {
                float a0 = 0.f, a1 = 0.f, a2 = 0.f, a3 = 0.f;
                const float* q0 = &q16[b4 * 4 + 0][h * 32];
                const float* q1 = &q16[b4 * 4 + 1][h * 32];
                const float* q2 = &q16[b4 * 4 + 2][h * 32];
                const float* q3 = &q16[b4 * 4 + 3][h * 32];
#pragma unroll
                for (int d = 0; d < 32; ++d) {
                    const float w = wkr[d];
                    a0 += q0[d] * w; a1 += q1[d] * w;
                    a2 += q2[d] * w; a3 += q3[d] * w;
                }
                op[(size_t)(b4 * 4 + 0) * 256] = a0 * RSQRT32;
                op[(size_t)(b4 * 4 + 1) * 256] = a1 * RSQRT32;
                op[(size_t)(b4 * 4 + 2) * 256] = a2 * RSQRT32;
                op[(size_t)(b4 * 4 + 3) * 256] = a3 * RSQRT32;
            }
        }
    } else if (bid < 896) {
        // ---- target-hash precompute: 16 (f,b) pairs per block ----
        const int pb = (bid - 768) * 16;           // global pair base
        const int f = pb >> 9, b0 = pb & 511;      // same f for whole block
        int* sid16 = (int*)smem;                   // [16]
        float (*tgt16)[64] = (float(*)[64])(smem + 16);
        if (t < 16) sid16[t] = oh_ids[(b0 + t) * 15 + f];
        __syncthreads();
        {
            const int r = t >> 4, c4 = (t & 15) << 2;
            *(float4*)&tgt16[r][c4] =
                *(const float4*)&oh_tab[((size_t)f * VOH + sid16[r]) * 64 + c4];
        }
        __syncthreads();
        const int lane = t & 63;
        const int bit = lane & 31;
#pragma unroll
        for (int it = 0; it < 2; ++it) {
            const int pl = (t >> 5) + it * 8;      // pair_local 0..15
            const float* tg = tgt16[pl];
            float acc = 0.f;
#pragma unroll
            for (int e = 0; e < 64; ++e) acc += tg[e] * hw[e * 32 + bit];
            const unsigned long long mm = __ballot(acc > 0.f);
            if (lane == 0)  thall[pb + pl] = (unsigned int)(mm & 0xFFFFFFFFull);
            if (lane == 32) thall[pb + pl] = (unsigned int)(mm >> 32);
        }
    } else if (bid < 1678) {
        // ---- LSH hash branch ----
        const int hb = bid - 896;
        float (*rows)[68] = (float(*)[68])smem;   // pitch 68: 16B-aligned b128
        const int lane = t & 63, wave = t >> 6;
        const int m = lane & 15, quad = lane >> 4;

        bf16x8 whf[2][2], wlf[2][2];
#pragma unroll
        for (int ks = 0; ks < 2; ++ks)
#pragma unroll
            for (int hf = 0; hf < 2; ++hf) {
                bf16x8 bh, bl;
#pragma unroll
                for (int j = 0; j < 8; ++j) {
                    const float w = hw[(ks * 32 + quad * 8 + j) * 32 + hf * 16 + m];
                    const __bf16 h = (__bf16)w;
                    bh[j] = h;
                    bl[j] = (__bf16)(w - (float)h);
                }
                whf[ks][hf] = bh; wlf[ks][hf] = bl;
            }

        const long long base_dw = (long long)hb * 32768;   // 512 rows * 64
        const long long lim = (long long)NROWS * 64;
        float4 pf[8];
#pragma unroll
        for (int i = 0; i < 8; ++i) {
            const long long idx = base_dw + i * 1024 + t * 4;
            pf[i] = make_float4(0.f, 0.f, 0.f, 0.f);
            if (idx < lim) pf[i] = *(const float4*)(tab + idx);
        }
        for (int c = 0; c < 4; ++c) {
            __syncthreads();              // prior chunk's LDS reads done
#pragma unroll
            for (int i = 0; i < 8; ++i) {
                const int v = t + i * 256;              // float4 index 0..2047
                *(float4*)&rows[v >> 4][(v & 15) << 2] = pf[i];
            }
            __syncthreads();
            if (c < 3) {                  // prefetch next chunk under compute
#pragma unroll
                for (int i = 0; i < 8; ++i) {
                    const long long idx = base_dw + (long long)(c + 1) * 8192 + i * 1024 + t * 4;
                    pf[i] = make_float4(0.f, 0.f, 0.f, 0.f);
                    if (idx < lim) pf[i] = *(const float4*)(tab + idx);
                }
            }
#pragma unroll
            for (int tile = 0; tile < 2; ++tile) {
                const int rbase = wave * 32 + tile * 16;
                f32x4 acc0 = {0.f, 0.f, 0.f, 0.f}, acc1 = {0.f, 0.f, 0.f, 0.f};
#pragma unroll
                for (int ks = 0; ks < 2; ++ks) {
                    const float* src = &rows[rbase + m][ks * 32 + quad * 8];
                    const float4 x0 = *(const float4*)(src);
                    const float4 x1 = *(const float4*)(src + 4);
                    float xs[8] = {x0.x, x0.y, x0.z, x0.w, x1.x, x1.y, x1.z, x1.w};
                    bf16x8 ah, al;
#pragma unroll
                    for (int j = 0; j < 8; ++j) {
                        const __bf16 hx = (__bf16)xs[j];
                        ah[j] = hx;
                        al[j] = (__bf16)(xs[j] - (float)hx);
                    }
                    acc0 = __builtin_amdgcn_mfma_f32_16x16x32_bf16(ah, whf[ks][0], acc0, 0, 0, 0);
                    acc0 = __builtin_amdgcn_mfma_f32_16x16x32_bf16(ah, wlf[ks][0], acc0, 0, 0, 0);
                    acc0 = __builtin_amdgcn_mfma_f32_16x16x32_bf16(al, whf[ks][0], acc0, 0, 0, 0);
                    acc1 = __builtin_amdgcn_mfma_f32_16x16x32_bf16(ah, whf[ks][1], acc1, 0, 0, 0);
                    acc1 = __builtin_amdgcn_mfma_f32_16x16x32_bf16(ah, wlf[ks][1], acc1, 0, 0, 0);
                    acc1 = __builtin_amdgcn_mfma_f32_16x16x32_bf16(al, whf[ks][1], acc1, 0, 0, 0);
                }
#pragma unroll
                for (int j = 0; j < 4; ++j) {
                    const unsigned long long m0 = __ballot(acc0[j] > 0.f);
                    const unsigned long long m1 = __ballot(acc1[j] > 0.f);
                    if (m == 0) {
                        const unsigned int bits =
                            (unsigned int)((m0 >> (quad * 16)) & 0xFFFFull) |
                            ((unsigned int)((m1 >> (quad * 16)) & 0xFFFFull) << 16);
                        const long long gr = (long long)hb * 512 + c * 128
                                           + rbase + quad * 4 + j;
                        if (gr < NROWS) sig[gr] = bits;
                    }
                }
            }
        }
    } else if (bid < 4046) {
        // ---- transpose branch ----
        const int tb = bid - 1678;
        const float* W; __bf16* WT; int N, K, base, nbs;
        if (tb < 1728)      { W = W0x; WT = WT0; K = 1728; N = 1024; base = 0;    nbs = 5; }
        else if (tb < 2240) { W = W1x; WT = WT1; K = 1024; N = 512;  base = 1728; nbs = 4; }
        else                 { W = W2x; WT = WT2; K = 512;  N = 256;  base = 2240; nbs = 3; }
        const int lb = tb - base;
        const int n0 = (lb & ((1 << nbs) - 1)) * 32, k0 = (lb >> nbs) * 32;
        float (*tile)[33] = (float(*)[33])smem;
        const int c = t & 31, r = t >> 5;
#pragma unroll
        for (int i = 0; i < 4; ++i)
            tile[r + 8 * i][c] = W[(size_t)(k0 + r + 8 * i) * N + n0 + c];
        __syncthreads();
#pragma unroll
        for (int i = 0; i < 4; ++i)
            WT[(size_t)(n0 + r + 8 * i) * K + k0 + c] = (__bf16)tile[c][r + 8 * i];
    } else {
        // ---- attn-weight fold branch (VO, bvo) ----
        const int idx = bid - 4046;
        const int f = idx & 3, z = (idx >> 2) & 1, h = idx >> 3;
        const float* WV = (z ? lvW : svW) + (size_t)f * 8192;
        const float* bv = (z ? lvb : svb) + f * 128;
        const float* WO = (z ? loW : soW) + (size_t)f * 8192;
        const float* bo = (z ? lob : sob) + f * 64;
        float (*wv)[33] = (float(*)[33])smem;
        float (*wo)[65] = (float(*)[65])(smem + 2112);
#pragma unroll
        for (int i = 0; i < 8; ++i) {
            int j = t + i * 256;
            wv[j >> 5][j & 31] = WV[(j >> 5) * 128 + h * 32 + (j & 31)];
            wo[j >> 6][j & 63] = WO[(h * 32 + (j >> 6)) * 64 + (j & 63)];
        }
        __syncthreads();
        const int lane = t & 63, grp = t >> 6;
        float* VOb = VO + (size_t)(((z * 4 + f) * 4 + h)) * 4096;
#pragma unroll 4
        for (int g = 0; g < 16; ++g) {
            const int ep = grp * 16 + g;
            float av = 0.f;
#pragma unroll
            for (int d = 0; d < 32; ++d) av += wv[ep][d] * wo[d][lane];
            VOb[ep * 64 + lane] = av;
        }
        if (h == 0 && t >= 64 && t < 128) {
            const int o = t - 64;
            float acc = bo[o];
            for (int a = 0; a < 128; ++a) acc += bv[a] * WO[a * 64 + o];
            bvo[(z * 4 + f) * 64 + o] = acc;
        }
    }
}

// ---------------------------------------------------------------------------
// K_ta (R12): merged top-K + attention. z=0 blocks: attention over the first
// 128 history ids. z=1 blocks: inline top-K (winners straight into LDS sid[],
// no global sel round-trip) then attention. Top-K gather latency overlaps
// other blocks' attention compute.
// ---------------------------------------------------------------------------
__global__ __launch_bounds__(256, 4) void k_ta(const float* __restrict__ mh_tab,
                                               const int* __restrict__ mh_ids,
                                               const unsigned int* __restrict__ sig,
                                               const unsigned int* __restrict__ thall,
                                               const float* __restrict__ qk_all,
                                               float* __restrict__ wembg)
{
    const int b = blockIdx.x, f = blockIdx.y, z = blockIdx.z, t = threadIdx.x;
    const int zf = z * 4 + f;
    const int lane = t & 63, wave = t >> 6;

    __shared__ float seq[128][65];
    __shared__ int   sid[128];
    __shared__ float qk[4][64];
    __shared__ float sc[4][128];
    __shared__ int hist[4][34];
    __shared__ int wtot[4];
    __shared__ int s_dstar, s_cntlt;

    if (z == 0) {
        if (t < 128) sid[t] = mh_ids[(size_t)(f * NB + b) * SEQ + t];
        __syncthreads();
    } else {
        // ---- inline top-K=128 by Hamming distance ----
        if (t < 136) ((int*)hist)[t] = 0;
        const unsigned int th = thall[f * NB + b];
        const int* idp = mh_ids + (size_t)(f * NB + b) * SEQ + t * 8;
        const int4 iv0 = *(const int4*)idp;
        const int4 iv1 = *(const int4*)(idp + 4);
        const int ids[8] = {iv0.x, iv0.y, iv0.z, iv0.w, iv1.x, iv1.y, iv1.z, iv1.w};
        int dv[8];
        const unsigned int* sb = sig + f * VMH;
#pragma unroll
        for (int j = 0; j < 8; ++j) {
            const int id = ids[j];
            const unsigned int s = sb[id >= 0 ? id : 0];
            dv[j] = (id >= 0) ? __popc(s ^ th) : 33;
        }
        __syncthreads();            // hist zero-init visible
#pragma unroll
        for (int j = 0; j < 8; ++j) atomicAdd(&hist[wave][dv[j]], 1);
        __syncthreads();
        if (t < 64) {               // wave 0: parallel bin scan + D* select
            const int tot = (t < 34) ? (hist[0][t] + hist[1][t] + hist[2][t] + hist[3][t]) : 0;
            int cum = tot;
#pragma unroll
            for (int off = 1; off < 64; off <<= 1) {
                const int u = __shfl_up(cum, off);
                if (t >= off) cum += u;
            }
            const unsigned long long mk = __ballot((t < 34) && (cum >= TOPK));
            const int ds = __ffsll(mk) - 1;
            if (t == ds) { s_dstar = ds; s_cntlt = cum - tot; }
        }
        __syncthreads();
        const int Dstar = s_dstar, cntlt = s_cntlt;
        int nlt = 0, neq = 0;
#pragma unroll
        for (int j = 0; j < 8; ++j) {
            nlt += (dv[j] < Dstar);
            neq += (dv[j] == Dstar);
        }
        int scan = (nlt << 16) | neq;
#pragma unroll
        for (int off = 1; off < 64; off <<= 1) {
            const int u = __shfl_up(scan, off);
            if (lane >= off) scan += u;
        }
        if (lane == 63) wtot[wave] = scan;
        __syncthreads();
        int pre = 0;
        for (int w = 0; w < wave; ++w) pre += wtot[w];
        scan += pre;
        int lt_pos = (scan >> 16) - nlt;             // exclusive prefix of nlt
        int eq_pos = cntlt + (scan & 0xFFFF) - neq;  // exclusive prefix of neq
#pragma unroll
        for (int j = 0; j < 8; ++j) {
            if (dv[j] < Dstar) { sid[lt_pos++] = ids[j]; }
            else if (dv[j] == Dstar) {
                if (eq_pos < TOPK) sid[eq_pos] = ids[j];
                eq_pos++;
            }
        }
        __syncthreads();            // sid[] complete
    }

    // ---- attention over sid[0..127] ----
    float4 g[8];
#pragma unroll
    for (int i = 0; i < 8; ++i) {
        const int v = t + i * 256;
        const int row = v >> 4, c4 = (v & 15) << 2;
        const int id = sid[row];
        g[i] = make_float4(0.f, 0.f, 0.f, 0.f);
        if (id >= 0) g[i] = *(const float4*)&mh_tab[((size_t)f * VMH + id) * 64 + c4];
    }
    ((float*)qk)[t] = qk_all[((size_t)zf * 512 + b) * 256 + t];
#pragma unroll
    for (int i = 0; i < 8; ++i) {
        const int v = t + i * 256;
        const int row = v >> 4, c4 = (v & 15) << 2;
        seq[row][c4 + 0] = g[i].x; seq[row][c4 + 1] = g[i].y;
        seq[row][c4 + 2] = g[i].z; seq[row][c4 + 3] = g[i].w;
    }
    __syncthreads();
#pragma unroll
    for (int rep = 0; rep < 2; ++rep) {
        const int idx = t + rep * 256;
        const int h = idx >> 7, s = idx & 127;
        float acc = 0.f;
#pragma unroll
        for (int e4 = 0; e4 < 16; ++e4) {
            const float4 q4 = *(const float4*)&qk[h][e4 * 4];
            acc += seq[s][e4 * 4 + 0] * q4.x + seq[s][e4 * 4 + 1] * q4.y
                 + seq[s][e4 * 4 + 2] * q4.z + seq[s][e4 * 4 + 3] * q4.w;
        }
        sc[h][s] = (sid[s] >= 0) ? acc : -INFINITY;
    }
    __syncthreads();
    {
        const int h = t >> 6, l = t & 63;
        float v0 = sc[h][l], v1 = sc[h][l + 64];
        float m = fmaxf(v0, v1);
        for (int off = 32; off; off >>= 1) m = fmaxf(m, __shfl_xor(m, off));
        float p0 = expf(v0 - m), p1 = expf(v1 - m);
        float ssum = p0 + p1;
        for (int off = 32; off; off >>= 1) ssum += __shfl_xor(ssum, off);
        float inv = 1.f / ssum;
        sc[h][l] = p0 * inv; sc[h][l + 64] = p1 * inv;
    }
    // wemb: same-wave reads of sc[h] (wave-synchronous, no barrier needed)
    {
        const int h = t >> 6, e = t & 63;
        float acc = 0.f;
#pragma unroll 8
        for (int s4 = 0; s4 < 32; ++s4) {
            const float4 a4 = *(const float4*)&sc[h][s4 * 4];
            acc += a4.x * seq[s4 * 4 + 0][e] + a4.y * seq[s4 * 4 + 1][e]
                 + a4.z * seq[s4 * 4 + 2][e] + a4.w * seq[s4 * 4 + 3][e];
        }
        wembg[((size_t)zf * 512 + b) * 256 + t] = acc;
    }
}

// ---------------------------------------------------------------------------
// K_wvo: out[b][o] = sum_{h,e} wemb[b][h*64+e] * VO[h][e][o] + bvo[o]
// ---------------------------------------------------------------------------
__global__ __launch_bounds__(256) void k_wvo(const float* __restrict__ wembg,
                                             const float* __restrict__ VO,
                                             const float* __restrict__ bvo,
                                             __bf16* __restrict__ feats)
{
    const int t = threadIdx.x;
    const int bc = blockIdx.x * 16, f = blockIdx.y, z = blockIdx.z;
    const int zf = z * 4 + f;
    __shared__ float wemb16[16][256];
    const float* src = wembg + ((size_t)zf * 512 + bc) * 256;
#pragma unroll
    for (int i = 0; i < 4; ++i) {
        const int v = t + i * 256;                 // float4 index 0..1023
        *(float4*)&wemb16[v >> 6][(v & 63) << 2] = *(const float4*)&src[v * 4];
    }
    __syncthreads();
    const int o = t & 63, bgrp = t >> 6;
    const float* VOb = VO + (size_t)zf * 4 * 4096;
    float a0 = 0.f, a1 = 0.f, a2 = 0.f, a3 = 0.f;
#pragma unroll
    for (int h = 0; h < 4; ++h) {
        const float* vr = VOb + h * 4096 + o;
#pragma unroll
        for (int e4 = 0; e4 < 16; ++e4) {
            const float v0 = vr[(e4 * 4 + 0) * 64];
            const float v1 = vr[(e4 * 4 + 1) * 64];
            const float v2 = vr[(e4 * 4 + 2) * 64];
            const float v3 = vr[(e4 * 4 + 3) * 64];
            const float4 w0 = *(const float4*)&wemb16[bgrp * 4 + 0][h * 64 + e4 * 4];
            const float4 w1 = *(const float4*)&wemb16[bgrp * 4 + 1][h * 64 + e4 * 4];
            const float4 w2 = *(const float4*)&wemb16[bgrp * 4 + 2][h * 64 + e4 * 4];
            const float4 w3 = *(const float4*)&wemb16[bgrp * 4 + 3][h * 64 + e4 * 4];
            a0 += w0.x * v0 + w0.y * v1 + w0.z * v2 + w0.w * v3;
            a1 += w1.x * v0 + w1.y * v1 + w1.z * v2 + w1.w * v3;
            a2 += w2.x * v0 + w2.y * v1 + w2.z * v2 + w2.w * v3;
            a3 += w3.x * v0 + w3.y * v1 + w3.z * v2 + w3.w * v3;
        }
    }
    const float bv = bvo[zf * 64 + o];
    const int col = (z ? 1472 : 1216) + f * 64 + o;
    feats[(size_t)(bc + bgrp * 4 + 0) * D0 + col] = (__bf16)(a0 + bv);
    feats[(size_t)(bc + bgrp * 4 + 1) * D0 + col] = (__bf16)(a1 + bv);
    feats[(size_t)(bc + bgrp * 4 + 2) * D0 + col] = (__bf16)(a2 + bv);
    feats[(size_t)(bc + bgrp * 4 + 3) * D0 + col] = (__bf16)(a3 + bv);
}

// ---------------------------------------------------------------------------
// K5b: bf16 MFMA GEMM. A [M,K] bf16 rm, BT [N,K] bf16 rm (pre-transposed),
// C = act(A@B + bias) as bf16 [M,N]. 64x64 tile, 4 waves = 2x2 of 32x32.
// ---------------------------------------------------------------------------
__global__ __launch_bounds__(256) void gemm_mfma(const __bf16* __restrict__ A,
                                                 const __bf16* __restrict__ BT,
                                                 const float* __restrict__ bias,
                                                 __bf16* __restrict__ C,
                                                 int M, int N, int K, int relu)
{
    __shared__ __bf16 As[64][72];
    __shared__ __bf16 Bs[64][72];
    const int t = threadIdx.x;
    const int n0 = blockIdx.x * 64, m0 = blockIdx.y * 64;
    const int wave = t >> 6, lane = t & 63;
    const int wm = (wave >> 1) * 32, wn = (wave & 1) * 32;
    const int row16 = lane & 15, quad = lane >> 4;
    f32x4 acc[2][2] = {};
    const int sr = t >> 3;
    const int sseg = (t & 7) * 8;
    for (int k0 = 0; k0 < K; k0 += 64) {
        bf16x8 av0 = *(const bf16x8*)&A[(size_t)(m0 + sr) * K + k0 + sseg];
        bf16x8 av1 = *(const bf16x8*)&A[(size_t)(m0 + sr + 32) * K + k0 + sseg];
        bf16x8 bv0 = *(const bf16x8*)&BT[(size_t)(n0 + sr) * K + k0 + sseg];
        bf16x8 bv1 = *(const bf16x8*)&BT[(size_t)(n0 + sr + 32) * K + k0 + sseg];
        __syncthreads();
        *(bf16x8*)&As[sr][sseg] = av0;
        *(bf16x8*)&As[sr + 32][sseg] = av1;
        *(bf16x8*)&Bs[sr][sseg] = bv0;
        *(bf16x8*)&Bs[sr + 32][sseg] = bv1;
        __syncthreads();
#pragma unroll
        for (int kk = 0; kk < 2; ++kk) {
            bf16x8 a0 = *(const bf16x8*)&As[wm + row16][kk * 32 + quad * 8];
            bf16x8 a1 = *(const bf16x8*)&As[wm + 16 + row16][kk * 32 + quad * 8];
            bf16x8 b0 = *(const bf16x8*)&Bs[wn + row16][kk * 32 + quad * 8];
            bf16x8 b1 = *(const bf16x8*)&Bs[wn + 16 + row16][kk * 32 + quad * 8];
            acc[0][0] = __builtin_amdgcn_mfma_f32_16x16x32_bf16(a0, b0, acc[0][0], 0, 0, 0);
            acc[0][1] = __builtin_amdgcn_mfma_f32_16x16x32_bf16(a0, b1, acc[0][1], 0, 0, 0);
            acc[1][0] = __builtin_amdgcn_mfma_f32_16x16x32_bf16(a1, b0, acc[1][0], 0, 0, 0);
            acc[1][1] = __builtin_amdgcn_mfma_f32_16x16x32_bf16(a1, b1, acc[1][1], 0, 0, 0);
        }
    }
#pragma unroll
    for (int i = 0; i < 2; ++i)
#pragma unroll
        for (int j = 0; j < 2; ++j) {
            const int col = n0 + wn + j * 16 + row16;
            const float bz = bias[col];
#pragma unroll
            for (int r = 0; r < 4; ++r) {
                const int rowm = m0 + wm + i * 16 + quad * 4 + r;
                float v = acc[i][j][r] + bz;
                if (relu) v = fmaxf(v, 0.f);
                C[(size_t)rowm * N + col] = (__bf16)v;
            }
        }
}

// ---------------------------------------------------------------------------
// K6: final 256-dot + bias + sigmoid (x2 bf16). One wave per batch row.
// ---------------------------------------------------------------------------
__global__ __launch_bounds__(256) void k_out(const __bf16* __restrict__ x2,
                                             const float* __restrict__ outW,
                                             const float* __restrict__ outb,
                                             float* __restrict__ out)
{
    const int t = threadIdx.x;
    const int wave = t >> 6, lane = t & 63;
    const int row = blockIdx.x * 4 + wave;
    bf16x4 xv = *(const bf16x4*)&x2[(size_t)row * 256 + lane * 4];
    const float4 wv = *(const float4*)&outW[lane * 4];
    float v = (float)xv[0] * wv.x + (float)xv[1] * wv.y
            + (float)xv[2] * wv.z + (float)xv[3] * wv.w;
    for (int off = 32; off; off >>= 1) v += __shfl_down(v, off);
    if (lane == 0) {
        float lg = v + outb[0];
        out[row] = 1.f / (1.f + expf(-lg));
        out[NB + row] = lg;
    }
}

// ---------------------------------------------------------------------------
extern "C" void kernel_launch(void* const* d_in, const int* in_sizes, int n_in,
                              void* d_out, int out_size, void* d_ws, size_t ws_size,
                              hipStream_t stream)
{
    const float* oh_tab = (const float*)d_in[0];
    const float* mh_tab = (const float*)d_in[1];
    const float* sp_tab = (const float*)d_in[2];
    const float* hw     = (const float*)d_in[3];
    const float* sqW = (const float*)d_in[4];  const float* sqb = (const float*)d_in[5];
    const float* skW = (const float*)d_in[6];  const float* skb = (const float*)d_in[7];
    const float* svW = (const float*)d_in[8];  const float* svb = (const float*)d_in[9];
    const float* soW = (const float*)d_in[10]; const float* sob = (const float*)d_in[11];
    const float* lqW = (const float*)d_in[12]; const float* lqb = (const float*)d_in[13];
    const float* lkW = (const float*)d_in[14]; const float* lkb = (const float*)d_in[15];
    const float* lvW = (const float*)d_in[16]; const float* lvb = (const float*)d_in[17];
    const float* loW = (const float*)d_in[18]; const float* lob = (const float*)d_in[19];
    const float* W0 = (const float*)d_in[20];  const float* b0 = (const float*)d_in[21];
    const float* W1 = (const float*)d_in[22];  const float* b1 = (const float*)d_in[23];
    const float* W2 = (const float*)d_in[24];  const float* b2 = (const float*)d_in[25];
    const float* outW = (const float*)d_in[26]; const float* outb = (const float*)d_in[27];
    const int* oh_ids = (const int*)d_in[28];
    const int* mh_ids = (const int*)d_in[29];
    const int* sp_ids = (const int*)d_in[30];
    (void)skb; (void)lkb;   // k-bias: per-head constant cancels in softmax

    char* ws = (char*)d_ws;
    unsigned int* sig = (unsigned int*)(ws + 0);            // 400128 * 4
    __bf16* feats = (__bf16*)(ws + 2649088);                // 884736 * 2
    __bf16* x0    = (__bf16*)(ws + 4418560);                // 524288 * 2
    __bf16* x1    = (__bf16*)(ws + 5467136);                // 262144 * 2
    __bf16* x2    = (__bf16*)(ws + 5991424);                // 131072 * 2
    __bf16* WT0   = (__bf16*)(ws + 6253568);                // 1769472 * 2
    __bf16* WT1   = (__bf16*)(ws + 9792512);                // 524288 * 2
    __bf16* WT2   = (__bf16*)(ws + 10841088);               // 131072 * 2
    float*  VO    = (float*) (ws + 11627520);               // 131072 * 4
    float*  bvo   = (float*) (ws + 12160000);               // 512 * 4
    float*  qk_all= (float*) (ws + 12162048);               // 1048576 * 4
    float*  wembg = (float*) (ws + 16356352);               // 1048576 * 4
    unsigned int* thall = (unsigned int*)(ws + 20550656);   // 2048 * 4
    // total ws usage: 20558848 bytes

    k_ph<<<4078, 256, 0, stream>>>(W0, W1, W2, WT0, WT1, WT2,
                                   sqW, sqb, skW, svW, svb, soW, sob,
                                   lqW, lqb, lkW, lvW, lvb, loW, lob,
                                   VO, bvo,
                                   mh_tab, hw, sig,
                                   oh_tab, oh_ids, thall,
                                   sp_tab, sp_ids, feats, qk_all);
    k_ta<<<dim3(NB, F_MH, 2), 256, 0, stream>>>(mh_tab, mh_ids, sig, thall,
                                                qk_all, wembg);
    k_wvo<<<dim3(32, F_MH, 2), 256, 0, stream>>>(wembg, VO, bvo, feats);
    gemm_mfma<<<dim3(16, 8), 256, 0, stream>>>(feats, WT0, b0, x0, 512, 1024, 1728, 1);
    gemm_mfma<<<dim3(8, 8), 256, 0, stream>>>(x0, WT1, b1, x1, 512, 512, 1024, 1);
    gemm_mfma<<<dim3(4, 8), 256, 0, stream>>>(x1, WT2, b2, x2, 512, 256, 512, 1);
    k_out<<<NB / 4, 256, 0, stream>>>(x2, outW, outb, (float*)d_out);
}